// Round 6
// baseline (422.400 us; speedup 1.0000x reference)
//
#include <hip/hip_runtime.h>
#include <hip/hip_bf16.h>

typedef unsigned short u16t;
typedef __attribute__((ext_vector_type(8))) short short8;
typedef __attribute__((ext_vector_type(8))) unsigned short ushort8;
typedef __attribute__((ext_vector_type(4))) unsigned short ushort4v;
typedef __attribute__((ext_vector_type(4))) float f32x4;

#define VTOT 1048576

__device__ __forceinline__ float bf2f(u16t u) {
  union { unsigned int i; float f; } v; v.i = ((unsigned int)u) << 16; return v.f;
}
__device__ __forceinline__ u16t f2bf(float f) {
  __hip_bfloat16 h = __float2bfloat16(f);
  union { __hip_bfloat16 b; u16t u; } v; v.b = h; return v.u;
}

// VGPR-form MFMA via inline asm: gfx950's unified RF allows C/D in arch VGPRs.
// The builtin path allocates accumulators in the AGPR class, and the compiler then
// splits every launch-bounds budget ~50/50 arch/AGPR (measured: lb2->124, lb3->84,
// lb4->64 arch), spilling whenever arch < ~115.  asm with "v" constraints creates
// zero AGPR virtual regs -> no split -> full budget is arch.
// Hazard padding (the compiler can't see inside asm): s_nop 1 before each MFMA
// (VALU-write -> MFMA-read src, 2 states); s_nop 7 after the LAST write of each
// accumulator (MFMA-write -> VALU-read).  Dependent VALU reads are dataflow-ordered
// after the whole asm, so the suffix must live in the same asm as the final MFMA.
#define MFMA_BF16(acc, a, b) \
  asm("s_nop 1\n\tv_mfma_f32_16x16x32_bf16 %0, %1, %2, %0" : "+v"(acc) : "v"(a), "v"(b))
#define MFMA_BF16_END(acc, a, b) \
  asm("s_nop 1\n\tv_mfma_f32_16x16x32_bf16 %0, %1, %2, %0\n\ts_nop 7" : "+v"(acc) : "v"(a), "v"(b))

// Kernel 1: sobel conv (bf16 LDS, fp32 accum) + fc0(relu) + fc1 via bf16 MFMA + stoch mask.
// R8: R6 structure + VGPR-form asm MFMA + lb(256,4).  Budget 128 arch vs ~115 need
// -> spill-free 4 waves/SIMD (16 waves/CU, occ ~50%).
// Post-mortem check: FETCH/WRITE must stay ~67/71MB (inflation = spills = revert to lb3).
__global__ __launch_bounds__(256, 4) void nca_main(
    const float* __restrict__ xg, const float* __restrict__ w0g,
    const float* __restrict__ b0g, const float* __restrict__ w1g,
    const float* __restrict__ stg, float* __restrict__ outg,
    float* __restrict__ aws, unsigned char* __restrict__ plife)
{
  // smem carve: [0..8704) u16 = xs halo [4][4][34][16]; [8704..16896) u16 = ys
  // [8 kchunks][128 vox][8]; whole [0..17408) u16 reused as h [128 vox][136] bf16.
  __shared__ u16t smem[17408];
  __shared__ float st_l[256];        // stoch fp32
  __shared__ float alpha_l[256];     // fp32 alpha(x2), staged for z3-max + coalesced aws flush
  __shared__ unsigned char pl_l[256];// pre_life bits

  const int t = threadIdx.x;
  const int bid = blockIdx.x;
  const int b = bid >> 10;
  const int z1base = ((bid >> 5) & 31) * 2;
  const int z2base = (bid & 31) * 2;

  {
    int z1 = t >> 7, z2 = (t >> 6) & 1, z3 = t & 63;
    int gv = ((b * 64 + z1base + z1) * 64 + (z2base + z2)) * 64 + z3;
    st_l[t] = stg[gv];
  }

  #pragma unroll 1
  for (int p = 0; p < 2; ++p) {
    asm volatile("" ::: "memory");
    if (p) __syncthreads();  // smem WAR vs previous pass fc1 h reads
    // stage x halo (fp32 -> bf16): 544 rows x 16 ch = 2176 float4 chunks
    for (int it = 0; it < 9; ++it) {
      int q = t + it * 256;
      if (q < 2176) {
        int c4 = (q & 3) * 4, s = q >> 2;
        int i3 = s % 34, r = s / 34;
        int i2 = r & 3, i1 = r >> 2;
        int z1g = z1base + i1 - 1, z2g = z2base + i2 - 1, z3g = p * 32 + i3 - 1;
        f32x4 val = {0.f, 0.f, 0.f, 0.f};
        if ((unsigned)z1g < 64u && (unsigned)z2g < 64u && (unsigned)z3g < 64u) {
          int gv = ((b * 64 + z1g) * 64 + z2g) * 64 + z3g;
          val = *(const f32x4*)(xg + gv * 16 + c4);
        }
        ushort4v bv;
        #pragma unroll
        for (int j = 0; j < 4; ++j) bv[j] = f2bf(val[j]);
        *(ushort4v*)(smem + s * 16 + c4) = bv;
      }
    }
    __syncthreads();
    // conv: one (voxel, channel-half) per thread; 128 voxels this pass
    {
      const int hc = t & 1, vp = t >> 1;
      const int z1 = vp >> 6, z2 = (vp >> 5) & 1, z3l = vp & 31;
      float ax[8], ay[8], az[8];
      #pragma unroll
      for (int c = 0; c < 8; ++c) { ax[c] = 0.f; ay[c] = 0.f; az[c] = 0.f; }
      ushort8 ctr{};
      float amax = 0.0f;  // alpha>=0 in x; 0-pad gives same >0.1 verdict as -inf pad
      const float W[3] = {1.f, 2.f, 1.f};
      const float D[3] = {-1.f, 0.f, 1.f};
      #pragma unroll
      for (int d1 = 0; d1 < 3; ++d1)
        #pragma unroll
        for (int d2 = 0; d2 < 3; ++d2)
          #pragma unroll
          for (int d3 = 0; d3 < 3; ++d3) {
            const int base = (((z1 + d1) * 4 + (z2 + d2)) * 34 + (z3l + d3)) * 16 + hc * 8;
            ushort8 u = *(const ushort8*)(smem + base);
            float f[8];
            #pragma unroll
            for (int c = 0; c < 8; ++c) f[c] = bf2f((u16t)u[c]);
            const float cx = W[d1] * W[d2] * D[d3] * 0.03125f;  // kx[k,i,j]=w[k]w[i]d[j]/32
            const float cy = W[d1] * D[d2] * W[d3] * 0.03125f;  // ky=kx.T(0,2,1)
            const float cz = D[d1] * W[d2] * W[d3] * 0.03125f;  // kz=kx.T(2,1,0)
            if (cx != 0.f) {
              #pragma unroll
              for (int c = 0; c < 8; ++c) ax[c] = fmaf(f[c], cx, ax[c]);
            }
            if (cy != 0.f) {
              #pragma unroll
              for (int c = 0; c < 8; ++c) ay[c] = fmaf(f[c], cy, ay[c]);
            }
            if (cz != 0.f) {
              #pragma unroll
              for (int c = 0; c < 8; ++c) az[c] = fmaf(f[c], cz, az[c]);
            }
            if (d1 == 1 && d2 == 1 && d3 == 1) ctr = u;
            amax = fmaxf(amax, f[3]);  // alpha = ch3 (meaningful for hc==0)
          }
      *(ushort8*)(smem + 8704 + (0 + hc) * 1024 + vp * 8) = ctr;
      ushort8 bx, by, bz;
      #pragma unroll
      for (int c = 0; c < 8; ++c) {
        bx[c] = (short)f2bf(ax[c]); by[c] = (short)f2bf(ay[c]); bz[c] = (short)f2bf(az[c]);
      }
      *(ushort8*)(smem + 8704 + (2 + hc) * 1024 + vp * 8) = bx;
      *(ushort8*)(smem + 8704 + (4 + hc) * 1024 + vp * 8) = by;
      *(ushort8*)(smem + 8704 + (6 + hc) * 1024 + vp * 8) = bz;
      if (hc == 0) pl_l[z1 * 128 + z2 * 64 + p * 32 + z3l] = (amax > 0.1f) ? (unsigned char)1 : (unsigned char)0;
    }
    __syncthreads();  // conv ys writes visible; xs halo now dead

    // GEMM phase, N-split: wave w owns h cols [w*32, w*32+32) for all 128 voxels.
    // fc0 swapped MFMA: D = mfma(A=w0f, B=yf) -> lane holds h[n=w*32+nt*16+quad*4+r][vox=mt*16+col].
    {
      const int lane = t & 63, w = t >> 6;
      const int col = lane & 15, quad = lane >> 4;
      // A-operand frags: w0f[kt][nt][j] = w0[w*32+nt*16+col][kt*32+quad*8+j]
      short8 w0f[2][2];
      #pragma unroll
      for (int kt = 0; kt < 2; ++kt)
        #pragma unroll
        for (int nt = 0; nt < 2; ++nt) {
          const float* pw = w0g + (w * 32 + nt * 16 + col) * 64 + kt * 32 + quad * 8;
          f32x4 lo = *(const f32x4*)pw, hi = *(const f32x4*)(pw + 4);
          short8 fr;
          #pragma unroll
          for (int j = 0; j < 4; ++j) { fr[j] = (short)f2bf(lo[j]); fr[4 + j] = (short)f2bf(hi[j]); }
          w0f[kt][nt] = fr;
        }
      // bias along the row (n) dim: biasv[nt][r] = b0[w*32+nt*16+quad*4+r]
      f32x4 biasv[2];
      #pragma unroll
      for (int nt = 0; nt < 2; ++nt)
        biasv[nt] = *(const f32x4*)(b0g + w * 32 + nt * 16 + quad * 4);

      ushort4v hpk[8][2];  // per-wave h slice, bf16-packed: 32 VGPRs
      #pragma unroll
      for (int mt = 0; mt < 8; ++mt) {
        short8 yf[2];  // B-operand: yf[kt][j] = y[mt*16+col][kt*32+quad*8+j]
        #pragma unroll
        for (int kt = 0; kt < 2; ++kt)
          yf[kt] = *(const short8*)(smem + 8704 + (kt * 4 + quad) * 1024 + (mt * 16 + col) * 8);
        f32x4 acc0 = biasv[0], acc1 = biasv[1];
        MFMA_BF16(acc0, w0f[0][0], yf[0]);
        MFMA_BF16(acc1, w0f[0][1], yf[0]);
        MFMA_BF16_END(acc0, w0f[1][0], yf[1]);  // last write of acc0
        MFMA_BF16_END(acc1, w0f[1][1], yf[1]);  // last write of acc1
        ushort4v hv0, hv1;
        #pragma unroll
        for (int r = 0; r < 4; ++r) {
          hv0[r] = f2bf(fmaxf(acc0[r], 0.0f));
          hv1[r] = f2bf(fmaxf(acc1[r], 0.0f));
        }
        hpk[mt][0] = hv0;
        hpk[mt][1] = hv1;
      }
      __syncthreads();  // all ys reads done (every wave) before h overlay clobbers smem
      // h dump: h[vox=mt*16+col][n=w*32+nt*16+quad*4 + 0..3] -> one b64 per (mt,nt)
      #pragma unroll
      for (int mt = 0; mt < 8; ++mt)
        #pragma unroll
        for (int nt = 0; nt < 2; ++nt)
          *(ushort4v*)(smem + (mt * 16 + col) * 136 + w * 32 + nt * 16 + quad * 4) = hpk[mt][nt];
      __syncthreads();  // h visible to all waves (fc1 reads all n for its voxels)

      // fc1: wave w handles voxels [w*32, w*32+32); K=128, N=16
      short8 w1f[4];  // B[k][n=col] = w1[col][k]
      #pragma unroll
      for (int kt = 0; kt < 4; ++kt) {
        const float* pw = w1g + col * 128 + kt * 32 + quad * 8;
        f32x4 lo = *(const f32x4*)pw, hi = *(const f32x4*)(pw + 4);
        short8 fr;
        #pragma unroll
        for (int j = 0; j < 4; ++j) { fr[j] = (short)f2bf(lo[j]); fr[4 + j] = (short)f2bf(hi[j]); }
        w1f[kt] = fr;
      }
      #pragma unroll
      for (int mt = 0; mt < 2; ++mt) {
        const int mbase = w * 32 + mt * 16;
        f32x4 dxa = {0.f, 0.f, 0.f, 0.f};
        short8 ah0 = *(const short8*)(smem + (mbase + col) * 136 + 0 * 32 + quad * 8);
        short8 ah1 = *(const short8*)(smem + (mbase + col) * 136 + 1 * 32 + quad * 8);
        short8 ah2 = *(const short8*)(smem + (mbase + col) * 136 + 2 * 32 + quad * 8);
        short8 ah3 = *(const short8*)(smem + (mbase + col) * 136 + 3 * 32 + quad * 8);
        MFMA_BF16(dxa, ah0, w1f[0]);
        MFMA_BF16(dxa, ah1, w1f[1]);
        MFMA_BF16(dxa, ah2, w1f[2]);
        MFMA_BF16_END(dxa, ah3, w1f[3]);  // last write of dxa
        // epilogue: out[v][col] = x[v][col] + mask*dx (xg re-read is L2/L3-hot)
        #pragma unroll
        for (int r = 0; r < 4; ++r) {
          const int vp = mbase + quad * 4 + r;
          const int z1 = vp >> 6, z2 = (vp >> 5) & 1, z3l = vp & 31;
          const int v = z1 * 128 + z2 * 64 + p * 32 + z3l;
          const int gv = ((b * 64 + z1base + z1) * 64 + (z2base + z2)) * 64 + p * 32 + z3l;
          const int addr = gv * 16 + col;
          float dx = (st_l[v] > 0.5f) ? dxa[r] : 0.0f;
          float x2 = xg[addr] + dx;
          outg[addr] = x2;
          if (col == 3) alpha_l[v] = x2;  // stage fp32 alpha(x2) in LDS
        }
      }
    }
  }
  __syncthreads();
  // coalesced aux flush; fold the z3 direction of the alive maxpool here:
  // aws[gv] = max(alpha[z3-1], alpha[z3], alpha[z3+1]) (domain edges -> -1e30 sentinel)
  if (aws != nullptr) {
    const int v = t, z3 = t & 63;
    const float a = alpha_l[v];
    const float up = (z3 > 0) ? alpha_l[v - 1] : -1e30f;
    const float dn = (z3 < 63) ? alpha_l[v + 1] : -1e30f;
    const int gv = ((b * 64 + z1base + (v >> 7)) * 64 + (z2base + ((v >> 6) & 1))) * 64 + z3;
    aws[gv] = fmaxf(a, fmaxf(up, dn));
    plife[gv] = pl_l[v];
  }
}

// Kernel 2: life = plife & (max over 3x3 (z1,z2) rows of z3-premaxed aws > 0.1);
// zero dead voxels in out.  Staging is 16 fully-coalesced 256B rows, no div/mod.
__global__ void nca_life(const float* __restrict__ aws,
                         const unsigned char* __restrict__ plife,
                         float* __restrict__ og)
{
  __shared__ float m3s[1024];  // [16 rows][64] z3-premaxed alpha(x2)
  const int t = threadIdx.x, bid = blockIdx.x;
  const int b = bid >> 10;
  const int z1base = ((bid >> 5) & 31) * 2;
  const int z2base = (bid & 31) * 2;
  #pragma unroll
  for (int it = 0; it < 4; ++it) {
    const int row = it * 4 + (t >> 6), z3 = t & 63;
    const int z1g = z1base + (row >> 2) - 1, z2g = z2base + (row & 3) - 1;
    float a = -1e30f;
    if ((unsigned)z1g < 64u && (unsigned)z2g < 64u)
      a = aws[((b * 64 + z1g) * 64 + z2g) * 64 + z3];
    m3s[row * 64 + z3] = a;
  }
  const int z1 = t >> 7, z2 = (t >> 6) & 1, z3 = t & 63;
  const int gv = ((b * 64 + z1base + z1) * 64 + (z2base + z2)) * 64 + z3;
  const unsigned char pl = plife[gv];  // issue early, hide under barrier
  __syncthreads();
  float mo = -1e30f;
  #pragma unroll
  for (int d1 = 0; d1 < 3; ++d1)
    #pragma unroll
    for (int d2 = 0; d2 < 3; ++d2)
      mo = fmaxf(mo, m3s[((z1 + d1) * 4 + (z2 + d2)) * 64 + z3]);
  const bool life = (pl != 0) && (mo > 0.1f);
  if (!life) {
    f32x4 z = {0.f, 0.f, 0.f, 0.f};
    #pragma unroll
    for (int j = 0; j < 4; ++j) *(f32x4*)(og + gv * 16 + j * 4) = z;
  }
}

// Fallback (no workspace): recompute both alive masks from strided global reads.
__global__ void nca_life_strided(const float* __restrict__ xg, const float* __restrict__ outg,
                                 float* __restrict__ og)
{
  __shared__ float a2x[1056];
  __shared__ float a2o[1056];
  const int t = threadIdx.x, bid = blockIdx.x;
  const int b = bid >> 10;
  const int z1base = ((bid >> 5) & 31) * 2;
  const int z2base = (bid & 31) * 2;
  for (int it = 0; it < 5; ++it) {
    int q = t + it * 256;
    if (q < 1056) {
      int i3 = q % 66, r = q / 66;
      int i2 = r & 3, i1 = r >> 2;
      int z1g = z1base + i1 - 1, z2g = z2base + i2 - 1, z3g = i3 - 1;
      float vx = 0.f, vo = 0.f;
      if ((unsigned)z1g < 64u && (unsigned)z2g < 64u && (unsigned)z3g < 64u) {
        int gv = ((b * 64 + z1g) * 64 + z2g) * 64 + z3g;
        vx = xg[gv * 16 + 3];
        vo = outg[gv * 16 + 3];
      }
      a2x[q] = vx; a2o[q] = vo;
    }
  }
  __syncthreads();
  const int z1 = t >> 7, z2 = (t >> 6) & 1, z3 = t & 63;
  float mx = -1e30f, mo = -1e30f;
  #pragma unroll
  for (int d1 = 0; d1 < 3; ++d1)
    #pragma unroll
    for (int d2 = 0; d2 < 3; ++d2)
      #pragma unroll
      for (int d3 = 0; d3 < 3; ++d3) {
        const int idx = ((z1 + d1) * 4 + (z2 + d2)) * 66 + (z3 + d3);
        mx = fmaxf(mx, a2x[idx]);
        mo = fmaxf(mo, a2o[idx]);
      }
  const bool life = (mx > 0.1f) && (mo > 0.1f);
  if (!life) {
    const int gv = ((b * 64 + z1base + z1) * 64 + (z2base + z2)) * 64 + z3;
    f32x4 z = {0.f, 0.f, 0.f, 0.f};
    #pragma unroll
    for (int j = 0; j < 4; ++j) *(f32x4*)(og + gv * 16 + j * 4) = z;
  }
}

extern "C" void kernel_launch(void* const* d_in, const int* in_sizes, int n_in,
                              void* d_out, int out_size, void* d_ws, size_t ws_size,
                              hipStream_t stream) {
  (void)out_size;
  const void *px = nullptr, *pw0 = nullptr, *pb0 = nullptr, *pw1 = nullptr, *pst = nullptr;
  for (int i = 0; i < n_in; ++i) {
    switch (in_sizes[i]) {
      case 16777216: px  = d_in[i]; break;  // x  [4,64,64,64,16]
      case 8192:     pw0 = d_in[i]; break;  // w0 [128,64]
      case 128:      pb0 = d_in[i]; break;  // b0 [128]
      case 2048:     pw1 = d_in[i]; break;  // w1 [16,128]
      case 1048576:  pst = d_in[i]; break;  // stoch [4,64,64,64,1]
    }
  }
  if (!px || !pw0 || !pb0 || !pw1 || !pst) {
    px = d_in[0]; pw0 = d_in[1]; pb0 = d_in[2]; pw1 = d_in[3]; pst = d_in[4];
  }
  float* outg = (float*)d_out;
  const size_t need = (size_t)VTOT * 4 + (size_t)VTOT;  // fp32 z3-max alpha + byte plife
  const bool use_ws = (d_ws != nullptr) && (ws_size >= need);
  float* aws = use_ws ? (float*)d_ws : nullptr;
  unsigned char* plife = use_ws ? ((unsigned char*)d_ws + (size_t)VTOT * 4) : nullptr;

  nca_main<<<4096, 256, 0, stream>>>((const float*)px, (const float*)pw0, (const float*)pb0,
                                     (const float*)pw1, (const float*)pst, outg, aws, plife);
  if (use_ws)
    nca_life<<<4096, 256, 0, stream>>>(aws, plife, outg);
  else
    nca_life_strided<<<4096, 256, 0, stream>>>((const float*)px, outg, outg);
}

// Round 7
// 351.557 us; speedup vs baseline: 1.2015x; 1.2015x over previous
//
#include <hip/hip_runtime.h>
#include <hip/hip_bf16.h>

typedef unsigned short u16t;
typedef __attribute__((ext_vector_type(8))) short short8;
typedef __attribute__((ext_vector_type(8))) unsigned short ushort8;
typedef __attribute__((ext_vector_type(4))) unsigned short ushort4v;
typedef __attribute__((ext_vector_type(4))) float f32x4;

#define VTOT 1048576

__device__ __forceinline__ float bf2f(u16t u) {
  union { unsigned int i; float f; } v; v.i = ((unsigned int)u) << 16; return v.f;
}
__device__ __forceinline__ u16t f2bf(float f) {
  __hip_bfloat16 h = __float2bfloat16(f);
  union { __hip_bfloat16 b; u16t u; } v; v.b = h; return v.u;
}

// Kernel 1: sobel conv (bf16 LDS, fp32 accum) + fc0(relu) + fc1 via bf16 MFMA + stoch mask.
// R9: fit the arch-VGPR half-budget instead of fighting it.
// Measured law (R4/R5/R7/R8): with ANY MFMA (builtin or asm) the backend caps arch
// VGPRs at launch-budget/2: lb2->124, lb3->84, lb4->64.  lb3 gives 3 waves/SIMD
// (occ 32%, R7) but R7 spilled: fc0 held hpk[8][2]=32 + w0f 16 + w1f 16 live.
// Fix: fc0 split into two mt-halves, hpk[4][2]=16 regs, each half dumped to the
// h buffer [128][136] immediately: rows 0..63 = bytes [0,8704) = dead xs region
// (no sync needed; ys untouched); rows 64..127 = [8704,17408) = ys region, dumped
// after the all-ys-reads barrier.  Peak arch ~75 < 85 -> spill-free at lb(256,3).
// Post-mortem check: FETCH/WRITE must stay ~67/71MB (inflation = spills = revert).
__global__ __launch_bounds__(256, 3) void nca_main(
    const float* __restrict__ xg, const float* __restrict__ w0g,
    const float* __restrict__ b0g, const float* __restrict__ w1g,
    const float* __restrict__ stg, float* __restrict__ outg,
    float* __restrict__ aws, unsigned char* __restrict__ plife)
{
  // smem carve: [0..8704) u16 = xs halo [4][4][34][16]; [8704..16896) u16 = ys
  // [8 kchunks][128 vox][8]; whole [0..17408) u16 reused as h [128 vox][136] bf16.
  __shared__ u16t smem[17408];
  __shared__ float st_l[256];        // stoch fp32
  __shared__ float alpha_l[256];     // fp32 alpha(x2), staged for z3-max + coalesced aws flush
  __shared__ unsigned char pl_l[256];// pre_life bits

  const int t = threadIdx.x;
  const int bid = blockIdx.x;
  const int b = bid >> 10;
  const int z1base = ((bid >> 5) & 31) * 2;
  const int z2base = (bid & 31) * 2;

  {
    int z1 = t >> 7, z2 = (t >> 6) & 1, z3 = t & 63;
    int gv = ((b * 64 + z1base + z1) * 64 + (z2base + z2)) * 64 + z3;
    st_l[t] = stg[gv];
  }

  #pragma unroll 1
  for (int p = 0; p < 2; ++p) {
    asm volatile("" ::: "memory");
    if (p) __syncthreads();  // smem WAR vs previous pass fc1 h reads
    // stage x halo (fp32 -> bf16): 544 rows x 16 ch = 2176 float4 chunks
    for (int it = 0; it < 9; ++it) {
      int q = t + it * 256;
      if (q < 2176) {
        int c4 = (q & 3) * 4, s = q >> 2;
        int i3 = s % 34, r = s / 34;
        int i2 = r & 3, i1 = r >> 2;
        int z1g = z1base + i1 - 1, z2g = z2base + i2 - 1, z3g = p * 32 + i3 - 1;
        f32x4 val = {0.f, 0.f, 0.f, 0.f};
        if ((unsigned)z1g < 64u && (unsigned)z2g < 64u && (unsigned)z3g < 64u) {
          int gv = ((b * 64 + z1g) * 64 + z2g) * 64 + z3g;
          val = *(const f32x4*)(xg + gv * 16 + c4);
        }
        ushort4v bv;
        #pragma unroll
        for (int j = 0; j < 4; ++j) bv[j] = f2bf(val[j]);
        *(ushort4v*)(smem + s * 16 + c4) = bv;
      }
    }
    __syncthreads();
    // conv: one (voxel, channel-half) per thread; 128 voxels this pass
    {
      const int hc = t & 1, vp = t >> 1;
      const int z1 = vp >> 6, z2 = (vp >> 5) & 1, z3l = vp & 31;
      float ax[8], ay[8], az[8];
      #pragma unroll
      for (int c = 0; c < 8; ++c) { ax[c] = 0.f; ay[c] = 0.f; az[c] = 0.f; }
      ushort8 ctr{};
      float amax = 0.0f;  // alpha>=0 in x; 0-pad gives same >0.1 verdict as -inf pad
      const float W[3] = {1.f, 2.f, 1.f};
      const float D[3] = {-1.f, 0.f, 1.f};
      #pragma unroll
      for (int d1 = 0; d1 < 3; ++d1)
        #pragma unroll
        for (int d2 = 0; d2 < 3; ++d2)
          #pragma unroll
          for (int d3 = 0; d3 < 3; ++d3) {
            const int base = (((z1 + d1) * 4 + (z2 + d2)) * 34 + (z3l + d3)) * 16 + hc * 8;
            ushort8 u = *(const ushort8*)(smem + base);
            float f[8];
            #pragma unroll
            for (int c = 0; c < 8; ++c) f[c] = bf2f((u16t)u[c]);
            const float cx = W[d1] * W[d2] * D[d3] * 0.03125f;  // kx[k,i,j]=w[k]w[i]d[j]/32
            const float cy = W[d1] * D[d2] * W[d3] * 0.03125f;  // ky=kx.T(0,2,1)
            const float cz = D[d1] * W[d2] * W[d3] * 0.03125f;  // kz=kx.T(2,1,0)
            if (cx != 0.f) {
              #pragma unroll
              for (int c = 0; c < 8; ++c) ax[c] = fmaf(f[c], cx, ax[c]);
            }
            if (cy != 0.f) {
              #pragma unroll
              for (int c = 0; c < 8; ++c) ay[c] = fmaf(f[c], cy, ay[c]);
            }
            if (cz != 0.f) {
              #pragma unroll
              for (int c = 0; c < 8; ++c) az[c] = fmaf(f[c], cz, az[c]);
            }
            if (d1 == 1 && d2 == 1 && d3 == 1) ctr = u;
            amax = fmaxf(amax, f[3]);  // alpha = ch3 (meaningful for hc==0)
          }
      *(ushort8*)(smem + 8704 + (0 + hc) * 1024 + vp * 8) = ctr;
      ushort8 bx, by, bz;
      #pragma unroll
      for (int c = 0; c < 8; ++c) {
        bx[c] = (short)f2bf(ax[c]); by[c] = (short)f2bf(ay[c]); bz[c] = (short)f2bf(az[c]);
      }
      *(ushort8*)(smem + 8704 + (2 + hc) * 1024 + vp * 8) = bx;
      *(ushort8*)(smem + 8704 + (4 + hc) * 1024 + vp * 8) = by;
      *(ushort8*)(smem + 8704 + (6 + hc) * 1024 + vp * 8) = bz;
      if (hc == 0) pl_l[z1 * 128 + z2 * 64 + p * 32 + z3l] = (amax > 0.1f) ? (unsigned char)1 : (unsigned char)0;
    }
    __syncthreads();  // conv ys writes visible; xs halo now dead

    // GEMM phase, N-split: wave w owns h cols [w*32, w*32+32) for all 128 voxels.
    // fc0 swapped MFMA: D = mfma(A=w0f, B=yf) -> lane holds h[n=w*32+nt*16+quad*4+r][vox=mt*16+col].
    // Two mt-halves; each half's hpk dumped immediately -> only 16 regs of h live.
    {
      const int lane = t & 63, w = t >> 6;
      const int col = lane & 15, quad = lane >> 4;
      // A-operand frags: w0f[kt][nt][j] = w0[w*32+nt*16+col][kt*32+quad*8+j]
      short8 w0f[2][2];
      #pragma unroll
      for (int kt = 0; kt < 2; ++kt)
        #pragma unroll
        for (int nt = 0; nt < 2; ++nt) {
          const float* pw = w0g + (w * 32 + nt * 16 + col) * 64 + kt * 32 + quad * 8;
          f32x4 lo = *(const f32x4*)pw, hi = *(const f32x4*)(pw + 4);
          short8 fr;
          #pragma unroll
          for (int j = 0; j < 4; ++j) { fr[j] = (short)f2bf(lo[j]); fr[4 + j] = (short)f2bf(hi[j]); }
          w0f[kt][nt] = fr;
        }
      // bias along the row (n) dim: biasv[nt][r] = b0[w*32+nt*16+quad*4+r]
      f32x4 biasv[2];
      #pragma unroll
      for (int nt = 0; nt < 2; ++nt)
        biasv[nt] = *(const f32x4*)(b0g + w * 32 + nt * 16 + quad * 4);

      ushort4v hpk[4][2];  // per-half h slice: 16 VGPRs

      // half A: vox 0..63 (mt 0..3)
      #pragma unroll
      for (int mt = 0; mt < 4; ++mt) {
        short8 yf[2];  // B-operand: yf[kt][j] = y[mt*16+col][kt*32+quad*8+j]
        #pragma unroll
        for (int kt = 0; kt < 2; ++kt)
          yf[kt] = *(const short8*)(smem + 8704 + (kt * 4 + quad) * 1024 + (mt * 16 + col) * 8);
        f32x4 acc[2];
        acc[0] = biasv[0]; acc[1] = biasv[1];
        #pragma unroll
        for (int kt = 0; kt < 2; ++kt)
          #pragma unroll
          for (int nt = 0; nt < 2; ++nt)
            acc[nt] = __builtin_amdgcn_mfma_f32_16x16x32_bf16(w0f[kt][nt], yf[kt], acc[nt], 0, 0, 0);
        #pragma unroll
        for (int nt = 0; nt < 2; ++nt) {
          ushort4v hv;
          #pragma unroll
          for (int r = 0; r < 4; ++r) hv[r] = f2bf(fmaxf(acc[nt][r], 0.0f));
          hpk[mt][nt] = hv;
        }
      }
      // dump half A: rows vox 0..63 -> bytes [0, 8704) = dead xs region (ys untouched,
      // so no barrier needed while other waves still read ys)
      #pragma unroll
      for (int mt = 0; mt < 4; ++mt)
        #pragma unroll
        for (int nt = 0; nt < 2; ++nt)
          *(ushort4v*)(smem + (mt * 16 + col) * 136 + w * 32 + nt * 16 + quad * 4) = hpk[mt][nt];

      // half B: vox 64..127 (mt 4..7), reusing hpk regs
      #pragma unroll
      for (int mt = 0; mt < 4; ++mt) {
        const int mtg = mt + 4;
        short8 yf[2];
        #pragma unroll
        for (int kt = 0; kt < 2; ++kt)
          yf[kt] = *(const short8*)(smem + 8704 + (kt * 4 + quad) * 1024 + (mtg * 16 + col) * 8);
        f32x4 acc[2];
        acc[0] = biasv[0]; acc[1] = biasv[1];
        #pragma unroll
        for (int kt = 0; kt < 2; ++kt)
          #pragma unroll
          for (int nt = 0; nt < 2; ++nt)
            acc[nt] = __builtin_amdgcn_mfma_f32_16x16x32_bf16(w0f[kt][nt], yf[kt], acc[nt], 0, 0, 0);
        #pragma unroll
        for (int nt = 0; nt < 2; ++nt) {
          ushort4v hv;
          #pragma unroll
          for (int r = 0; r < 4; ++r) hv[r] = f2bf(fmaxf(acc[nt][r], 0.0f));
          hpk[mt][nt] = hv;
        }
      }
      __syncthreads();  // all waves' ys reads done; half-A dump visible
      // dump half B: rows vox 64..127 -> bytes [8704, 17408) = now-dead ys region
      #pragma unroll
      for (int mt = 0; mt < 4; ++mt)
        #pragma unroll
        for (int nt = 0; nt < 2; ++nt)
          *(ushort4v*)(smem + ((mt + 4) * 16 + col) * 136 + w * 32 + nt * 16 + quad * 4) = hpk[mt][nt];
      __syncthreads();  // full h visible to all waves

      // fc1: wave w handles voxels [w*32, w*32+32); K=128, N=16
      short8 w1f[4];  // B[k][n=col] = w1[col][k]
      #pragma unroll
      for (int kt = 0; kt < 4; ++kt) {
        const float* pw = w1g + col * 128 + kt * 32 + quad * 8;
        f32x4 lo = *(const f32x4*)pw, hi = *(const f32x4*)(pw + 4);
        short8 fr;
        #pragma unroll
        for (int j = 0; j < 4; ++j) { fr[j] = (short)f2bf(lo[j]); fr[4 + j] = (short)f2bf(hi[j]); }
        w1f[kt] = fr;
      }
      #pragma unroll
      for (int mt = 0; mt < 2; ++mt) {
        const int mbase = w * 32 + mt * 16;
        f32x4 dxa = {0.f, 0.f, 0.f, 0.f};
        #pragma unroll
        for (int kt = 0; kt < 4; ++kt) {
          short8 ah = *(const short8*)(smem + (mbase + col) * 136 + kt * 32 + quad * 8);
          dxa = __builtin_amdgcn_mfma_f32_16x16x32_bf16(ah, w1f[kt], dxa, 0, 0, 0);
        }
        // epilogue: out[v][col] = x[v][col] + mask*dx (xg re-read is L2/L3-hot)
        #pragma unroll
        for (int r = 0; r < 4; ++r) {
          const int vp = mbase + quad * 4 + r;
          const int z1 = vp >> 6, z2 = (vp >> 5) & 1, z3l = vp & 31;
          const int v = z1 * 128 + z2 * 64 + p * 32 + z3l;
          const int gv = ((b * 64 + z1base + z1) * 64 + (z2base + z2)) * 64 + p * 32 + z3l;
          const int addr = gv * 16 + col;
          float dx = (st_l[v] > 0.5f) ? dxa[r] : 0.0f;
          float x2 = xg[addr] + dx;
          outg[addr] = x2;
          if (col == 3) alpha_l[v] = x2;  // stage fp32 alpha(x2) in LDS
        }
      }
    }
  }
  __syncthreads();
  // coalesced aux flush; fold the z3 direction of the alive maxpool here:
  // aws[gv] = max(alpha[z3-1], alpha[z3], alpha[z3+1]) (domain edges -> -1e30 sentinel)
  if (aws != nullptr) {
    const int v = t, z3 = t & 63;
    const float a = alpha_l[v];
    const float up = (z3 > 0) ? alpha_l[v - 1] : -1e30f;
    const float dn = (z3 < 63) ? alpha_l[v + 1] : -1e30f;
    const int gv = ((b * 64 + z1base + (v >> 7)) * 64 + (z2base + ((v >> 6) & 1))) * 64 + z3;
    aws[gv] = fmaxf(a, fmaxf(up, dn));
    plife[gv] = pl_l[v];
  }
}

// Kernel 2 (R9: 4 tiles/block): life = plife & (max over 3x3 (z1,z2) rows of
// z3-premaxed aws > 0.1); zero dead voxels.  Each block: 4x4 (z1,z2) x 64 z3
// = 1024 voxels; halo staging 36 rows (vs 64 over 4 separate blocks); grid 1024.
__global__ void nca_life(const float* __restrict__ aws,
                         const unsigned char* __restrict__ plife,
                         float* __restrict__ og)
{
  __shared__ float m3s[2304];  // [36 rows][64] z3-premaxed alpha(x2)
  const int t = threadIdx.x, bid = blockIdx.x;
  const int b = bid >> 8;
  const int z1b = ((bid >> 4) & 15) * 4;
  const int z2b = (bid & 15) * 4;
  #pragma unroll
  for (int it = 0; it < 9; ++it) {
    const int q = t + it * 256;           // 0..2303
    const int row = q >> 6, z3 = q & 63;  // row = r1*6 + r2, 6x6 halo grid
    const int r1 = z1b + (row / 6) - 1, r2 = z2b + (row % 6) - 1;
    float a = -1e30f;
    if ((unsigned)r1 < 64u && (unsigned)r2 < 64u)
      a = aws[((b * 64 + r1) * 64 + r2) * 64 + z3];
    m3s[q] = a;
  }
  // prefetch plife (coalesced) while staging is in flight
  unsigned char pl[4]; int gvs[4];
  #pragma unroll
  for (int k = 0; k < 4; ++k) {
    const int v = t + k * 256;
    const int z1l = v >> 8, z2l = (v >> 6) & 3, z3 = v & 63;
    gvs[k] = ((b * 64 + z1b + z1l) * 64 + (z2b + z2l)) * 64 + z3;
    pl[k] = plife[gvs[k]];
  }
  __syncthreads();
  #pragma unroll
  for (int k = 0; k < 4; ++k) {
    const int v = t + k * 256;
    const int z1l = v >> 8, z2l = (v >> 6) & 3, z3 = v & 63;
    float mo = -1e30f;
    #pragma unroll
    for (int d1 = 0; d1 < 3; ++d1)
      #pragma unroll
      for (int d2 = 0; d2 < 3; ++d2)
        mo = fmaxf(mo, m3s[((z1l + d1) * 6 + (z2l + d2)) * 64 + z3]);
    const bool life = (pl[k] != 0) && (mo > 0.1f);
    if (!life) {
      f32x4 z = {0.f, 0.f, 0.f, 0.f};
      #pragma unroll
      for (int j = 0; j < 4; ++j) *(f32x4*)(og + gvs[k] * 16 + j * 4) = z;
    }
  }
}

// Fallback (no workspace): recompute both alive masks from strided global reads.
__global__ void nca_life_strided(const float* __restrict__ xg, const float* __restrict__ outg,
                                 float* __restrict__ og)
{
  __shared__ float a2x[1056];
  __shared__ float a2o[1056];
  const int t = threadIdx.x, bid = blockIdx.x;
  const int b = bid >> 10;
  const int z1base = ((bid >> 5) & 31) * 2;
  const int z2base = (bid & 31) * 2;
  for (int it = 0; it < 5; ++it) {
    int q = t + it * 256;
    if (q < 1056) {
      int i3 = q % 66, r = q / 66;
      int i2 = r & 3, i1 = r >> 2;
      int z1g = z1base + i1 - 1, z2g = z2base + i2 - 1, z3g = i3 - 1;
      float vx = 0.f, vo = 0.f;
      if ((unsigned)z1g < 64u && (unsigned)z2g < 64u && (unsigned)z3g < 64u) {
        int gv = ((b * 64 + z1g) * 64 + z2g) * 64 + z3g;
        vx = xg[gv * 16 + 3];
        vo = outg[gv * 16 + 3];
      }
      a2x[q] = vx; a2o[q] = vo;
    }
  }
  __syncthreads();
  const int z1 = t >> 7, z2 = (t >> 6) & 1, z3 = t & 63;
  float mx = -1e30f, mo = -1e30f;
  #pragma unroll
  for (int d1 = 0; d1 < 3; ++d1)
    #pragma unroll
    for (int d2 = 0; d2 < 3; ++d2)
      #pragma unroll
      for (int d3 = 0; d3 < 3; ++d3) {
        const int idx = ((z1 + d1) * 4 + (z2 + d2)) * 66 + (z3 + d3);
        mx = fmaxf(mx, a2x[idx]);
        mo = fmaxf(mo, a2o[idx]);
      }
  const bool life = (mx > 0.1f) && (mo > 0.1f);
  if (!life) {
    const int gv = ((b * 64 + z1base + z1) * 64 + (z2base + z2)) * 64 + z3;
    f32x4 z = {0.f, 0.f, 0.f, 0.f};
    #pragma unroll
    for (int j = 0; j < 4; ++j) *(f32x4*)(og + gv * 16 + j * 4) = z;
  }
}

extern "C" void kernel_launch(void* const* d_in, const int* in_sizes, int n_in,
                              void* d_out, int out_size, void* d_ws, size_t ws_size,
                              hipStream_t stream) {
  (void)out_size;
  const void *px = nullptr, *pw0 = nullptr, *pb0 = nullptr, *pw1 = nullptr, *pst = nullptr;
  for (int i = 0; i < n_in; ++i) {
    switch (in_sizes[i]) {
      case 16777216: px  = d_in[i]; break;  // x  [4,64,64,64,16]
      case 8192:     pw0 = d_in[i]; break;  // w0 [128,64]
      case 128:      pb0 = d_in[i]; break;  // b0 [128]
      case 2048:     pw1 = d_in[i]; break;  // w1 [16,128]
      case 1048576:  pst = d_in[i]; break;  // stoch [4,64,64,64,1]
    }
  }
  if (!px || !pw0 || !pb0 || !pw1 || !pst) {
    px = d_in[0]; pw0 = d_in[1]; pb0 = d_in[2]; pw1 = d_in[3]; pst = d_in[4];
  }
  float* outg = (float*)d_out;
  const size_t need = (size_t)VTOT * 4 + (size_t)VTOT;  // fp32 z3-max alpha + byte plife
  const bool use_ws = (d_ws != nullptr) && (ws_size >= need);
  float* aws = use_ws ? (float*)d_ws : nullptr;
  unsigned char* plife = use_ws ? ((unsigned char*)d_ws + (size_t)VTOT * 4) : nullptr;

  nca_main<<<4096, 256, 0, stream>>>((const float*)px, (const float*)pw0, (const float*)pb0,
                                     (const float*)pw1, (const float*)pst, outg, aws, plife);
  if (use_ws)
    nca_life<<<1024, 256, 0, stream>>>(aws, plife, outg);
  else
    nca_life_strided<<<4096, 256, 0, stream>>>((const float*)px, outg, outg);
}

// Round 8
// 271.994 us; speedup vs baseline: 1.5530x; 1.2925x over previous
//
#include <hip/hip_runtime.h>
#include <hip/hip_bf16.h>

typedef unsigned short u16t;
typedef __attribute__((ext_vector_type(8))) short short8;
typedef __attribute__((ext_vector_type(8))) unsigned short ushort8;
typedef __attribute__((ext_vector_type(4))) unsigned short ushort4v;
typedef __attribute__((ext_vector_type(4))) float f32x4;

#define VTOT 1048576

__device__ __forceinline__ float bf2f(u16t u) {
  union { unsigned int i; float f; } v; v.i = ((unsigned int)u) << 16; return v.f;
}
__device__ __forceinline__ u16t f2bf(float f) {
  __hip_bfloat16 h = __float2bfloat16(f);
  union { __hip_bfloat16 b; u16t u; } v; v.b = h; return v.u;
}

// Kernel 1: sobel conv (bf16 LDS, fp32 accum) + fc0(relu) + fc1 via bf16 MFMA + stoch mask.
// R10: exact R6 structure (best: 185us) + amdgpu_num_vgpr(112).
// Ladder so far: lb2 -> 124 arch (+~10 AGPR = ~134 combined, just OVER the 128
// occupancy cliff -> 2 waves/SIMD, occ 22%); lb3/lb4 -> backend splits budget 50/50
// arch/AGPR (84/64 arch) -> unavoidable spills (R7/R9 identical spill volume proves
// the spilled values aren't the ones we restructured).  num_vgpr(112) caps arch
// directly WITHOUT the 50/50 split: combined 112+~12 <= 128 -> 4 waves/SIMD.
// True arch need ~100-110 (R6 spill-free at 124) -> expect spill-free at 112.
// Post-mortem tripwire: FETCH/WRITE must stay ~67/71MB; big inflation = revert.
__global__ __launch_bounds__(256, 2) __attribute__((amdgpu_num_vgpr(112))) void nca_main(
    const float* __restrict__ xg, const float* __restrict__ w0g,
    const float* __restrict__ b0g, const float* __restrict__ w1g,
    const float* __restrict__ stg, float* __restrict__ outg,
    float* __restrict__ aws, unsigned char* __restrict__ plife)
{
  // smem carve: [0..8704) u16 = xs halo [4][4][34][16]; [8704..16896) u16 = ys
  // [8 kchunks][128 vox][8]; whole [0..17408) u16 reused as h [128 vox][136] bf16.
  __shared__ u16t smem[17408];
  __shared__ float st_l[256];        // stoch fp32
  __shared__ float alpha_l[256];     // fp32 alpha(x2), staged for z3-max + coalesced aws flush
  __shared__ unsigned char pl_l[256];// pre_life bits

  const int t = threadIdx.x;
  const int bid = blockIdx.x;
  const int b = bid >> 10;
  const int z1base = ((bid >> 5) & 31) * 2;
  const int z2base = (bid & 31) * 2;

  {
    int z1 = t >> 7, z2 = (t >> 6) & 1, z3 = t & 63;
    int gv = ((b * 64 + z1base + z1) * 64 + (z2base + z2)) * 64 + z3;
    st_l[t] = stg[gv];
  }

  #pragma unroll 1
  for (int p = 0; p < 2; ++p) {
    asm volatile("" ::: "memory");
    if (p) __syncthreads();  // smem WAR vs previous pass fc1 h reads
    // stage x halo (fp32 -> bf16): 544 rows x 16 ch = 2176 float4 chunks
    for (int it = 0; it < 9; ++it) {
      int q = t + it * 256;
      if (q < 2176) {
        int c4 = (q & 3) * 4, s = q >> 2;
        int i3 = s % 34, r = s / 34;
        int i2 = r & 3, i1 = r >> 2;
        int z1g = z1base + i1 - 1, z2g = z2base + i2 - 1, z3g = p * 32 + i3 - 1;
        f32x4 val = {0.f, 0.f, 0.f, 0.f};
        if ((unsigned)z1g < 64u && (unsigned)z2g < 64u && (unsigned)z3g < 64u) {
          int gv = ((b * 64 + z1g) * 64 + z2g) * 64 + z3g;
          val = *(const f32x4*)(xg + gv * 16 + c4);
        }
        ushort4v bv;
        #pragma unroll
        for (int j = 0; j < 4; ++j) bv[j] = f2bf(val[j]);
        *(ushort4v*)(smem + s * 16 + c4) = bv;
      }
    }
    __syncthreads();
    // conv: one (voxel, channel-half) per thread; 128 voxels this pass
    {
      const int hc = t & 1, vp = t >> 1;
      const int z1 = vp >> 6, z2 = (vp >> 5) & 1, z3l = vp & 31;
      float ax[8], ay[8], az[8];
      #pragma unroll
      for (int c = 0; c < 8; ++c) { ax[c] = 0.f; ay[c] = 0.f; az[c] = 0.f; }
      ushort8 ctr{};
      float amax = 0.0f;  // alpha>=0 in x; 0-pad gives same >0.1 verdict as -inf pad
      const float W[3] = {1.f, 2.f, 1.f};
      const float D[3] = {-1.f, 0.f, 1.f};
      #pragma unroll
      for (int d1 = 0; d1 < 3; ++d1)
        #pragma unroll
        for (int d2 = 0; d2 < 3; ++d2)
          #pragma unroll
          for (int d3 = 0; d3 < 3; ++d3) {
            const int base = (((z1 + d1) * 4 + (z2 + d2)) * 34 + (z3l + d3)) * 16 + hc * 8;
            ushort8 u = *(const ushort8*)(smem + base);
            float f[8];
            #pragma unroll
            for (int c = 0; c < 8; ++c) f[c] = bf2f((u16t)u[c]);
            const float cx = W[d1] * W[d2] * D[d3] * 0.03125f;  // kx[k,i,j]=w[k]w[i]d[j]/32
            const float cy = W[d1] * D[d2] * W[d3] * 0.03125f;  // ky=kx.T(0,2,1)
            const float cz = D[d1] * W[d2] * W[d3] * 0.03125f;  // kz=kx.T(2,1,0)
            if (cx != 0.f) {
              #pragma unroll
              for (int c = 0; c < 8; ++c) ax[c] = fmaf(f[c], cx, ax[c]);
            }
            if (cy != 0.f) {
              #pragma unroll
              for (int c = 0; c < 8; ++c) ay[c] = fmaf(f[c], cy, ay[c]);
            }
            if (cz != 0.f) {
              #pragma unroll
              for (int c = 0; c < 8; ++c) az[c] = fmaf(f[c], cz, az[c]);
            }
            if (d1 == 1 && d2 == 1 && d3 == 1) ctr = u;
            amax = fmaxf(amax, f[3]);  // alpha = ch3 (meaningful for hc==0)
          }
      *(ushort8*)(smem + 8704 + (0 + hc) * 1024 + vp * 8) = ctr;
      ushort8 bx, by, bz;
      #pragma unroll
      for (int c = 0; c < 8; ++c) {
        bx[c] = (short)f2bf(ax[c]); by[c] = (short)f2bf(ay[c]); bz[c] = (short)f2bf(az[c]);
      }
      *(ushort8*)(smem + 8704 + (2 + hc) * 1024 + vp * 8) = bx;
      *(ushort8*)(smem + 8704 + (4 + hc) * 1024 + vp * 8) = by;
      *(ushort8*)(smem + 8704 + (6 + hc) * 1024 + vp * 8) = bz;
      if (hc == 0) pl_l[z1 * 128 + z2 * 64 + p * 32 + z3l] = (amax > 0.1f) ? (unsigned char)1 : (unsigned char)0;
    }
    __syncthreads();  // conv ys writes visible; xs halo now dead

    // GEMM phase, N-split: wave w owns h cols [w*32, w*32+32) for all 128 voxels.
    // fc0 swapped MFMA: D = mfma(A=w0f, B=yf) -> lane holds h[n=w*32+nt*16+quad*4+r][vox=mt*16+col].
    {
      const int lane = t & 63, w = t >> 6;
      const int col = lane & 15, quad = lane >> 4;
      // A-operand frags: w0f[kt][nt][j] = w0[w*32+nt*16+col][kt*32+quad*8+j]
      short8 w0f[2][2];
      #pragma unroll
      for (int kt = 0; kt < 2; ++kt)
        #pragma unroll
        for (int nt = 0; nt < 2; ++nt) {
          const float* pw = w0g + (w * 32 + nt * 16 + col) * 64 + kt * 32 + quad * 8;
          f32x4 lo = *(const f32x4*)pw, hi = *(const f32x4*)(pw + 4);
          short8 fr;
          #pragma unroll
          for (int j = 0; j < 4; ++j) { fr[j] = (short)f2bf(lo[j]); fr[4 + j] = (short)f2bf(hi[j]); }
          w0f[kt][nt] = fr;
        }
      // bias along the row (n) dim: biasv[nt][r] = b0[w*32+nt*16+quad*4+r]
      f32x4 biasv[2];
      #pragma unroll
      for (int nt = 0; nt < 2; ++nt)
        biasv[nt] = *(const f32x4*)(b0g + w * 32 + nt * 16 + quad * 4);

      ushort4v hpk[8][2];  // per-wave h slice, bf16-packed: 32 VGPRs
      #pragma unroll
      for (int mt = 0; mt < 8; ++mt) {
        short8 yf[2];  // B-operand: yf[kt][j] = y[mt*16+col][kt*32+quad*8+j]
        #pragma unroll
        for (int kt = 0; kt < 2; ++kt)
          yf[kt] = *(const short8*)(smem + 8704 + (kt * 4 + quad) * 1024 + (mt * 16 + col) * 8);
        f32x4 acc[2];
        acc[0] = biasv[0]; acc[1] = biasv[1];
        #pragma unroll
        for (int kt = 0; kt < 2; ++kt)
          #pragma unroll
          for (int nt = 0; nt < 2; ++nt)
            acc[nt] = __builtin_amdgcn_mfma_f32_16x16x32_bf16(w0f[kt][nt], yf[kt], acc[nt], 0, 0, 0);
        #pragma unroll
        for (int nt = 0; nt < 2; ++nt) {
          ushort4v hv;
          #pragma unroll
          for (int r = 0; r < 4; ++r) hv[r] = f2bf(fmaxf(acc[nt][r], 0.0f));
          hpk[mt][nt] = hv;
        }
      }
      __syncthreads();  // all ys reads done (every wave) before h overlay clobbers smem
      // h dump: h[vox=mt*16+col][n=w*32+nt*16+quad*4 + 0..3] -> one b64 per (mt,nt)
      #pragma unroll
      for (int mt = 0; mt < 8; ++mt)
        #pragma unroll
        for (int nt = 0; nt < 2; ++nt)
          *(ushort4v*)(smem + (mt * 16 + col) * 136 + w * 32 + nt * 16 + quad * 4) = hpk[mt][nt];
      __syncthreads();  // h visible to all waves (fc1 reads all n for its voxels)

      // fc1: wave w handles voxels [w*32, w*32+32); K=128, N=16
      short8 w1f[4];  // B[k][n=col] = w1[col][k]
      #pragma unroll
      for (int kt = 0; kt < 4; ++kt) {
        const float* pw = w1g + col * 128 + kt * 32 + quad * 8;
        f32x4 lo = *(const f32x4*)pw, hi = *(const f32x4*)(pw + 4);
        short8 fr;
        #pragma unroll
        for (int j = 0; j < 4; ++j) { fr[j] = (short)f2bf(lo[j]); fr[4 + j] = (short)f2bf(hi[j]); }
        w1f[kt] = fr;
      }
      #pragma unroll
      for (int mt = 0; mt < 2; ++mt) {
        const int mbase = w * 32 + mt * 16;
        f32x4 dxa = {0.f, 0.f, 0.f, 0.f};
        #pragma unroll
        for (int kt = 0; kt < 4; ++kt) {
          short8 ah = *(const short8*)(smem + (mbase + col) * 136 + kt * 32 + quad * 8);
          dxa = __builtin_amdgcn_mfma_f32_16x16x32_bf16(ah, w1f[kt], dxa, 0, 0, 0);
        }
        // epilogue: out[v][col] = x[v][col] + mask*dx (xg re-read is L2/L3-hot)
        #pragma unroll
        for (int r = 0; r < 4; ++r) {
          const int vp = mbase + quad * 4 + r;
          const int z1 = vp >> 6, z2 = (vp >> 5) & 1, z3l = vp & 31;
          const int v = z1 * 128 + z2 * 64 + p * 32 + z3l;
          const int gv = ((b * 64 + z1base + z1) * 64 + (z2base + z2)) * 64 + p * 32 + z3l;
          const int addr = gv * 16 + col;
          float dx = (st_l[v] > 0.5f) ? dxa[r] : 0.0f;
          float x2 = xg[addr] + dx;
          outg[addr] = x2;
          if (col == 3) alpha_l[v] = x2;  // stage fp32 alpha(x2) in LDS
        }
      }
    }
  }
  __syncthreads();
  // coalesced aux flush; fold the z3 direction of the alive maxpool here:
  // aws[gv] = max(alpha[z3-1], alpha[z3], alpha[z3+1]) (domain edges -> -1e30 sentinel)
  if (aws != nullptr) {
    const int v = t, z3 = t & 63;
    const float a = alpha_l[v];
    const float up = (z3 > 0) ? alpha_l[v - 1] : -1e30f;
    const float dn = (z3 < 63) ? alpha_l[v + 1] : -1e30f;
    const int gv = ((b * 64 + z1base + (v >> 7)) * 64 + (z2base + ((v >> 6) & 1))) * 64 + z3;
    aws[gv] = fmaxf(a, fmaxf(up, dn));
    plife[gv] = pl_l[v];
  }
}

// Kernel 2: life = plife & (max over 3x3 (z1,z2) rows of z3-premaxed aws > 0.1);
// zero dead voxels in out.  Staging is 16 fully-coalesced 256B rows, no div/mod.
__global__ void nca_life(const float* __restrict__ aws,
                         const unsigned char* __restrict__ plife,
                         float* __restrict__ og)
{
  __shared__ float m3s[1024];  // [16 rows][64] z3-premaxed alpha(x2)
  const int t = threadIdx.x, bid = blockIdx.x;
  const int b = bid >> 10;
  const int z1base = ((bid >> 5) & 31) * 2;
  const int z2base = (bid & 31) * 2;
  #pragma unroll
  for (int it = 0; it < 4; ++it) {
    const int row = it * 4 + (t >> 6), z3 = t & 63;
    const int z1g = z1base + (row >> 2) - 1, z2g = z2base + (row & 3) - 1;
    float a = -1e30f;
    if ((unsigned)z1g < 64u && (unsigned)z2g < 64u)
      a = aws[((b * 64 + z1g) * 64 + z2g) * 64 + z3];
    m3s[row * 64 + z3] = a;
  }
  const int z1 = t >> 7, z2 = (t >> 6) & 1, z3 = t & 63;
  const int gv = ((b * 64 + z1base + z1) * 64 + (z2base + z2)) * 64 + z3;
  const unsigned char pl = plife[gv];  // issue early, hide under barrier
  __syncthreads();
  float mo = -1e30f;
  #pragma unroll
  for (int d1 = 0; d1 < 3; ++d1)
    #pragma unroll
    for (int d2 = 0; d2 < 3; ++d2)
      mo = fmaxf(mo, m3s[((z1 + d1) * 4 + (z2 + d2)) * 64 + z3]);
  const bool life = (pl != 0) && (mo > 0.1f);
  if (!life) {
    f32x4 z = {0.f, 0.f, 0.f, 0.f};
    #pragma unroll
    for (int j = 0; j < 4; ++j) *(f32x4*)(og + gv * 16 + j * 4) = z;
  }
}

// Fallback (no workspace): recompute both alive masks from strided global reads.
__global__ void nca_life_strided(const float* __restrict__ xg, const float* __restrict__ outg,
                                 float* __restrict__ og)
{
  __shared__ float a2x[1056];
  __shared__ float a2o[1056];
  const int t = threadIdx.x, bid = blockIdx.x;
  const int b = bid >> 10;
  const int z1base = ((bid >> 5) & 31) * 2;
  const int z2base = (bid & 31) * 2;
  for (int it = 0; it < 5; ++it) {
    int q = t + it * 256;
    if (q < 1056) {
      int i3 = q % 66, r = q / 66;
      int i2 = r & 3, i1 = r >> 2;
      int z1g = z1base + i1 - 1, z2g = z2base + i2 - 1, z3g = i3 - 1;
      float vx = 0.f, vo = 0.f;
      if ((unsigned)z1g < 64u && (unsigned)z2g < 64u && (unsigned)z3g < 64u) {
        int gv = ((b * 64 + z1g) * 64 + z2g) * 64 + z3g;
        vx = xg[gv * 16 + 3];
        vo = outg[gv * 16 + 3];
      }
      a2x[q] = vx; a2o[q] = vo;
    }
  }
  __syncthreads();
  const int z1 = t >> 7, z2 = (t >> 6) & 1, z3 = t & 63;
  float mx = -1e30f, mo = -1e30f;
  #pragma unroll
  for (int d1 = 0; d1 < 3; ++d1)
    #pragma unroll
    for (int d2 = 0; d2 < 3; ++d2)
      #pragma unroll
      for (int d3 = 0; d3 < 3; ++d3) {
        const int idx = ((z1 + d1) * 4 + (z2 + d2)) * 66 + (z3 + d3);
        mx = fmaxf(mx, a2x[idx]);
        mo = fmaxf(mo, a2o[idx]);
      }
  const bool life = (mx > 0.1f) && (mo > 0.1f);
  if (!life) {
    const int gv = ((b * 64 + z1base + z1) * 64 + (z2base + z2)) * 64 + z3;
    f32x4 z = {0.f, 0.f, 0.f, 0.f};
    #pragma unroll
    for (int j = 0; j < 4; ++j) *(f32x4*)(og + gv * 16 + j * 4) = z;
  }
}

extern "C" void kernel_launch(void* const* d_in, const int* in_sizes, int n_in,
                              void* d_out, int out_size, void* d_ws, size_t ws_size,
                              hipStream_t stream) {
  (void)out_size;
  const void *px = nullptr, *pw0 = nullptr, *pb0 = nullptr, *pw1 = nullptr, *pst = nullptr;
  for (int i = 0; i < n_in; ++i) {
    switch (in_sizes[i]) {
      case 16777216: px  = d_in[i]; break;  // x  [4,64,64,64,16]
      case 8192:     pw0 = d_in[i]; break;  // w0 [128,64]
      case 128:      pb0 = d_in[i]; break;  // b0 [128]
      case 2048:     pw1 = d_in[i]; break;  // w1 [16,128]
      case 1048576:  pst = d_in[i]; break;  // stoch [4,64,64,64,1]
    }
  }
  if (!px || !pw0 || !pb0 || !pw1 || !pst) {
    px = d_in[0]; pw0 = d_in[1]; pb0 = d_in[2]; pw1 = d_in[3]; pst = d_in[4];
  }
  float* outg = (float*)d_out;
  const size_t need = (size_t)VTOT * 4 + (size_t)VTOT;  // fp32 z3-max alpha + byte plife
  const bool use_ws = (d_ws != nullptr) && (ws_size >= need);
  float* aws = use_ws ? (float*)d_ws : nullptr;
  unsigned char* plife = use_ws ? ((unsigned char*)d_ws + (size_t)VTOT * 4) : nullptr;

  nca_main<<<4096, 256, 0, stream>>>((const float*)px, (const float*)pw0, (const float*)pb0,
                                     (const float*)pw1, (const float*)pst, outg, aws, plife);
  if (use_ws)
    nca_life<<<4096, 256, 0, stream>>>(aws, plife, outg);
  else
    nca_life_strided<<<4096, 256, 0, stream>>>((const float*)px, outg, outg);
}

// Round 9
// 246.698 us; speedup vs baseline: 1.7122x; 1.1025x over previous
//
#include <hip/hip_runtime.h>
#include <hip/hip_bf16.h>

typedef unsigned short u16t;
typedef __attribute__((ext_vector_type(8))) short short8;
typedef __attribute__((ext_vector_type(8))) unsigned short ushort8;
typedef __attribute__((ext_vector_type(4))) unsigned short ushort4v;
typedef __attribute__((ext_vector_type(4))) float f32x4;

#define VTOT 1048576

__device__ __forceinline__ float bf2f(u16t u) {
  union { unsigned int i; float f; } v; v.i = ((unsigned int)u) << 16; return v.f;
}
__device__ __forceinline__ u16t f2bf(float f) {
  __hip_bfloat16 h = __float2bfloat16(f);
  union { __hip_bfloat16 b; u16t u; } v; v.b = h; return v.u;
}

// Kernel 1: sobel conv (bf16 LDS, fp32 accum) + fc0(relu) + fc1 via bf16 MFMA + stoch mask.
// R11: single z3-pass.  Register law (R4-R10, fully mapped): with MFMA present the
// backend reserves arch+AGPR = the full waves_per_eu budget, so HW occupancy ==
// declared waves_per_eu and arch regs == budget/2; only lb2 is spill-free (need
// ~105-115).  => occupancy capped at 2 blocks/CU BY REGISTERS; LDS up to 80KB is
// free.  Spend it: whole 2x2x64 tile in one pass -> halo staged once, barriers
// 10 -> 6.  Buffers: xs[4][4][66][16] 33.8KB + ys[8][256][8] 32KB; h[256][136]
// (69.6KB) overlays xs+ys.  fc0 in two vox-halves (hpk = 32 regs): half-A h-rows
// 0..127 end at u16 17,408 < ys[kc0][vox128] at 17,920 -> clobbers only dead xs +
// dead ys[kc0][vox<64]; half-B dumped after its reads-done barrier.
// Spill tripwire: FETCH/WRITE must stay ~67/71MB.
__global__ __launch_bounds__(256, 2) void nca_main(
    const float* __restrict__ xg, const float* __restrict__ w0g,
    const float* __restrict__ b0g, const float* __restrict__ w1g,
    const float* __restrict__ stg, float* __restrict__ outg,
    float* __restrict__ aws, unsigned char* __restrict__ plife)
{
  // region A (u16 idx): xs @0 [16 rows(z1,z2)][66 z3][16ch] = 16,896;
  // ys @16,896 [8 kc][256 vox][8] = 16,384; h overlay @0 [256][136] = 34,816.
  __shared__ u16t smem[34816];
  __shared__ float st_l[256];
  __shared__ float alpha_l[256];
  __shared__ unsigned char pl_l[256];

  const int t = threadIdx.x;
  const int bid = blockIdx.x;
  const int b = bid >> 10;
  const int z1base = ((bid >> 5) & 31) * 2;
  const int z2base = (bid & 31) * 2;
  const int YO = 16896;  // ys base (u16)

  {
    int z1 = t >> 7, z2 = (t >> 6) & 1, z3 = t & 63;
    int gv = ((b * 64 + z1base + z1) * 64 + (z2base + z2)) * 64 + z3;
    st_l[t] = stg[gv];
  }

  // stage x halo (fp32 -> bf16): 1056 rows x 16 ch = 4224 float4 chunks
  for (int it = 0; it < 17; ++it) {
    int q = t + it * 256;
    if (q < 4224) {
      int c4 = (q & 3) * 4, s = q >> 2;
      int i3 = s % 66, r = s / 66;
      int i2 = r & 3, i1 = r >> 2;
      int z1g = z1base + i1 - 1, z2g = z2base + i2 - 1, z3g = i3 - 1;
      f32x4 val = {0.f, 0.f, 0.f, 0.f};
      if ((unsigned)z1g < 64u && (unsigned)z2g < 64u && (unsigned)z3g < 64u) {
        int gv = ((b * 64 + z1g) * 64 + z2g) * 64 + z3g;
        val = *(const f32x4*)(xg + gv * 16 + c4);
      }
      ushort4v bv;
      #pragma unroll
      for (int j = 0; j < 4; ++j) bv[j] = f2bf(val[j]);
      *(ushort4v*)(smem + s * 16 + c4) = bv;
    }
  }
  __syncthreads();  // B1: halo staged

  // conv: 512 (vox, channel-half) pairs; 2 per thread (vox vp and vp+128)
  #pragma unroll 1
  for (int half = 0; half < 2; ++half) {
    const int hc = t & 1;
    const int vp = (t >> 1) + half * 128;
    const int z1 = half, z2 = (vp >> 6) & 1, z3 = vp & 63;
    float ax[8], ay[8], az[8];
    #pragma unroll
    for (int c = 0; c < 8; ++c) { ax[c] = 0.f; ay[c] = 0.f; az[c] = 0.f; }
    ushort8 ctr{};
    float amax = 0.0f;  // alpha>=0 in x; 0-pad gives same >0.1 verdict as -inf pad
    const float W[3] = {1.f, 2.f, 1.f};
    const float D[3] = {-1.f, 0.f, 1.f};
    #pragma unroll
    for (int d1 = 0; d1 < 3; ++d1)
      #pragma unroll
      for (int d2 = 0; d2 < 3; ++d2)
        #pragma unroll
        for (int d3 = 0; d3 < 3; ++d3) {
          const int row = ((z1 + d1) * 4 + (z2 + d2)) * 66 + (z3 + d3);
          ushort8 u = *(const ushort8*)(smem + row * 16 + hc * 8);
          float f[8];
          #pragma unroll
          for (int c = 0; c < 8; ++c) f[c] = bf2f((u16t)u[c]);
          const float cx = W[d1] * W[d2] * D[d3] * 0.03125f;  // kx[k,i,j]=w[k]w[i]d[j]/32
          const float cy = W[d1] * D[d2] * W[d3] * 0.03125f;  // ky=kx.T(0,2,1)
          const float cz = D[d1] * W[d2] * W[d3] * 0.03125f;  // kz=kx.T(2,1,0)
          if (cx != 0.f) {
            #pragma unroll
            for (int c = 0; c < 8; ++c) ax[c] = fmaf(f[c], cx, ax[c]);
          }
          if (cy != 0.f) {
            #pragma unroll
            for (int c = 0; c < 8; ++c) ay[c] = fmaf(f[c], cy, ay[c]);
          }
          if (cz != 0.f) {
            #pragma unroll
            for (int c = 0; c < 8; ++c) az[c] = fmaf(f[c], cz, az[c]);
          }
          if (d1 == 1 && d2 == 1 && d3 == 1) ctr = u;
          amax = fmaxf(amax, f[3]);  // alpha = ch3 (meaningful for hc==0)
        }
    *(ushort8*)(smem + YO + (0 + hc) * 2048 + vp * 8) = ctr;
    ushort8 bx, by, bz;
    #pragma unroll
    for (int c = 0; c < 8; ++c) {
      bx[c] = (short)f2bf(ax[c]); by[c] = (short)f2bf(ay[c]); bz[c] = (short)f2bf(az[c]);
    }
    *(ushort8*)(smem + YO + (2 + hc) * 2048 + vp * 8) = bx;
    *(ushort8*)(smem + YO + (4 + hc) * 2048 + vp * 8) = by;
    *(ushort8*)(smem + YO + (6 + hc) * 2048 + vp * 8) = bz;
    if (hc == 0) pl_l[vp] = (amax > 0.1f) ? (unsigned char)1 : (unsigned char)0;
  }
  __syncthreads();  // B2: ys complete; xs dead

  // GEMM, N-split fc0: wave w owns h cols [w*32, w*32+32) for all 256 voxels.
  // Swapped MFMA: lane holds h[n=w*32+nt*16+quad*4+r][vox=...+col].
  {
    const int lane = t & 63, w = t >> 6;
    const int col = lane & 15, quad = lane >> 4;
    short8 w0f[2][2];  // w0f[kt][nt][j] = w0[w*32+nt*16+col][kt*32+quad*8+j]
    #pragma unroll
    for (int kt = 0; kt < 2; ++kt)
      #pragma unroll
      for (int nt = 0; nt < 2; ++nt) {
        const float* pw = w0g + (w * 32 + nt * 16 + col) * 64 + kt * 32 + quad * 8;
        f32x4 lo = *(const f32x4*)pw, hi = *(const f32x4*)(pw + 4);
        short8 fr;
        #pragma unroll
        for (int j = 0; j < 4; ++j) { fr[j] = (short)f2bf(lo[j]); fr[4 + j] = (short)f2bf(hi[j]); }
        w0f[kt][nt] = fr;
      }
    f32x4 biasv[2];  // biasv[nt][r] = b0[w*32+nt*16+quad*4+r]
    #pragma unroll
    for (int nt = 0; nt < 2; ++nt)
      biasv[nt] = *(const f32x4*)(b0g + w * 32 + nt * 16 + quad * 4);

    ushort4v hpk[8][2];  // one vox-half of the wave's h slice: 32 VGPRs

    // fc0 half A: vox 0..127 (mt 0..7)
    #pragma unroll
    for (int mt = 0; mt < 8; ++mt) {
      short8 yf[2];
      #pragma unroll
      for (int kt = 0; kt < 2; ++kt)
        yf[kt] = *(const short8*)(smem + YO + (kt * 4 + quad) * 2048 + (mt * 16 + col) * 8);
      f32x4 acc[2];
      acc[0] = biasv[0]; acc[1] = biasv[1];
      #pragma unroll
      for (int kt = 0; kt < 2; ++kt)
        #pragma unroll
        for (int nt = 0; nt < 2; ++nt)
          acc[nt] = __builtin_amdgcn_mfma_f32_16x16x32_bf16(w0f[kt][nt], yf[kt], acc[nt], 0, 0, 0);
      #pragma unroll
      for (int nt = 0; nt < 2; ++nt) {
        ushort4v hv;
        #pragma unroll
        for (int r = 0; r < 4; ++r) hv[r] = f2bf(fmaxf(acc[nt][r], 0.0f));
        hpk[mt][nt] = hv;
      }
    }
    __syncthreads();  // B3: all waves done reading ys vox 0..127
    // dump half A: h rows 0..127 -> u16 [0, 17,408) (dead xs + dead ys[kc0][vox<64])
    #pragma unroll
    for (int mt = 0; mt < 8; ++mt)
      #pragma unroll
      for (int nt = 0; nt < 2; ++nt)
        *(ushort4v*)(smem + (mt * 16 + col) * 136 + w * 32 + nt * 16 + quad * 4) = hpk[mt][nt];

    // fc0 half B: vox 128..255 (ys regions >= u16 17,920, untouched by dump A)
    #pragma unroll
    for (int mt = 0; mt < 8; ++mt) {
      short8 yf[2];
      #pragma unroll
      for (int kt = 0; kt < 2; ++kt)
        yf[kt] = *(const short8*)(smem + YO + (kt * 4 + quad) * 2048 + (128 + mt * 16 + col) * 8);
      f32x4 acc[2];
      acc[0] = biasv[0]; acc[1] = biasv[1];
      #pragma unroll
      for (int kt = 0; kt < 2; ++kt)
        #pragma unroll
        for (int nt = 0; nt < 2; ++nt)
          acc[nt] = __builtin_amdgcn_mfma_f32_16x16x32_bf16(w0f[kt][nt], yf[kt], acc[nt], 0, 0, 0);
      #pragma unroll
      for (int nt = 0; nt < 2; ++nt) {
        ushort4v hv;
        #pragma unroll
        for (int r = 0; r < 4; ++r) hv[r] = f2bf(fmaxf(acc[nt][r], 0.0f));
        hpk[mt][nt] = hv;
      }
    }
    __syncthreads();  // B4: all waves done reading ys vox 128..255; dump A visible
    // dump half B: h rows 128..255
    #pragma unroll
    for (int mt = 0; mt < 8; ++mt)
      #pragma unroll
      for (int nt = 0; nt < 2; ++nt)
        *(ushort4v*)(smem + (128 + mt * 16 + col) * 136 + w * 32 + nt * 16 + quad * 4) = hpk[mt][nt];
    __syncthreads();  // B5: full h visible

    // fc1: wave w handles vox [w*64, w*64+64); K=128, N=16
    short8 w1f[4];  // B[k][n=col] = w1[col][k]
    #pragma unroll
    for (int kt = 0; kt < 4; ++kt) {
      const float* pw = w1g + col * 128 + kt * 32 + quad * 8;
      f32x4 lo = *(const f32x4*)pw, hi = *(const f32x4*)(pw + 4);
      short8 fr;
      #pragma unroll
      for (int j = 0; j < 4; ++j) { fr[j] = (short)f2bf(lo[j]); fr[4 + j] = (short)f2bf(hi[j]); }
      w1f[kt] = fr;
    }
    #pragma unroll
    for (int mt2 = 0; mt2 < 4; ++mt2) {
      const int mbase = w * 64 + mt2 * 16;
      f32x4 dxa = {0.f, 0.f, 0.f, 0.f};
      #pragma unroll
      for (int kt = 0; kt < 4; ++kt) {
        short8 ah = *(const short8*)(smem + (mbase + col) * 136 + kt * 32 + quad * 8);
        dxa = __builtin_amdgcn_mfma_f32_16x16x32_bf16(ah, w1f[kt], dxa, 0, 0, 0);
      }
      // epilogue: out[v][col] = x[v][col] + mask*dx (xg re-read is L2/L3-hot)
      #pragma unroll
      for (int r = 0; r < 4; ++r) {
        const int v = mbase + quad * 4 + r;
        const int z1 = v >> 7, z2 = (v >> 6) & 1, z3 = v & 63;
        const int gv = ((b * 64 + z1base + z1) * 64 + (z2base + z2)) * 64 + z3;
        const int addr = gv * 16 + col;
        float dx = (st_l[v] > 0.5f) ? dxa[r] : 0.0f;
        float x2 = xg[addr] + dx;
        outg[addr] = x2;
        if (col == 3) alpha_l[v] = x2;  // stage fp32 alpha(x2) in LDS
      }
    }
  }
  __syncthreads();  // B6
  // coalesced aux flush; fold the z3 direction of the alive maxpool here:
  // aws[gv] = max(alpha[z3-1], alpha[z3], alpha[z3+1]) (domain edges -> -1e30 sentinel)
  if (aws != nullptr) {
    const int v = t, z3 = t & 63;
    const float a = alpha_l[v];
    const float up = (z3 > 0) ? alpha_l[v - 1] : -1e30f;
    const float dn = (z3 < 63) ? alpha_l[v + 1] : -1e30f;
    const int gv = ((b * 64 + z1base + (v >> 7)) * 64 + (z2base + ((v >> 6) & 1))) * 64 + z3;
    aws[gv] = fmaxf(a, fmaxf(up, dn));
    plife[gv] = pl_l[v];
  }
}

// Kernel 2 (4 tiles/block): life = plife & (max over 3x3 (z1,z2) rows of
// z3-premaxed aws > 0.1); zero dead voxels.  Each block: 4x4 (z1,z2) x 64 z3
// = 1024 voxels; halo staging 36 rows (vs 64 over 4 separate blocks); grid 1024.
__global__ void nca_life(const float* __restrict__ aws,
                         const unsigned char* __restrict__ plife,
                         float* __restrict__ og)
{
  __shared__ float m3s[2304];  // [36 rows][64] z3-premaxed alpha(x2)
  const int t = threadIdx.x, bid = blockIdx.x;
  const int b = bid >> 8;
  const int z1b = ((bid >> 4) & 15) * 4;
  const int z2b = (bid & 15) * 4;
  #pragma unroll
  for (int it = 0; it < 9; ++it) {
    const int q = t + it * 256;           // 0..2303
    const int row = q >> 6, z3 = q & 63;  // row = r1*6 + r2, 6x6 halo grid
    const int r1 = z1b + (row / 6) - 1, r2 = z2b + (row % 6) - 1;
    float a = -1e30f;
    if ((unsigned)r1 < 64u && (unsigned)r2 < 64u)
      a = aws[((b * 64 + r1) * 64 + r2) * 64 + z3];
    m3s[q] = a;
  }
  // prefetch plife (coalesced) while staging is in flight
  unsigned char pl[4]; int gvs[4];
  #pragma unroll
  for (int k = 0; k < 4; ++k) {
    const int v = t + k * 256;
    const int z1l = v >> 8, z2l = (v >> 6) & 3, z3 = v & 63;
    gvs[k] = ((b * 64 + z1b + z1l) * 64 + (z2b + z2l)) * 64 + z3;
    pl[k] = plife[gvs[k]];
  }
  __syncthreads();
  #pragma unroll
  for (int k = 0; k < 4; ++k) {
    const int v = t + k * 256;
    const int z1l = v >> 8, z2l = (v >> 6) & 3, z3 = v & 63;
    float mo = -1e30f;
    #pragma unroll
    for (int d1 = 0; d1 < 3; ++d1)
      #pragma unroll
      for (int d2 = 0; d2 < 3; ++d2)
        mo = fmaxf(mo, m3s[((z1l + d1) * 6 + (z2l + d2)) * 64 + z3]);
    const bool life = (pl[k] != 0) && (mo > 0.1f);
    if (!life) {
      f32x4 z = {0.f, 0.f, 0.f, 0.f};
      #pragma unroll
      for (int j = 0; j < 4; ++j) *(f32x4*)(og + gvs[k] * 16 + j * 4) = z;
    }
  }
}

// Fallback (no workspace): recompute both alive masks from strided global reads.
__global__ void nca_life_strided(const float* __restrict__ xg, const float* __restrict__ outg,
                                 float* __restrict__ og)
{
  __shared__ float a2x[1056];
  __shared__ float a2o[1056];
  const int t = threadIdx.x, bid = blockIdx.x;
  const int b = bid >> 10;
  const int z1base = ((bid >> 5) & 31) * 2;
  const int z2base = (bid & 31) * 2;
  for (int it = 0; it < 5; ++it) {
    int q = t + it * 256;
    if (q < 1056) {
      int i3 = q % 66, r = q / 66;
      int i2 = r & 3, i1 = r >> 2;
      int z1g = z1base + i1 - 1, z2g = z2base + i2 - 1, z3g = i3 - 1;
      float vx = 0.f, vo = 0.f;
      if ((unsigned)z1g < 64u && (unsigned)z2g < 64u && (unsigned)z3g < 64u) {
        int gv = ((b * 64 + z1g) * 64 + z2g) * 64 + z3g;
        vx = xg[gv * 16 + 3];
        vo = outg[gv * 16 + 3];
      }
      a2x[q] = vx; a2o[q] = vo;
    }
  }
  __syncthreads();
  const int z1 = t >> 7, z2 = (t >> 6) & 1, z3 = t & 63;
  float mx = -1e30f, mo = -1e30f;
  #pragma unroll
  for (int d1 = 0; d1 < 3; ++d1)
    #pragma unroll
    for (int d2 = 0; d2 < 3; ++d2)
      #pragma unroll
      for (int d3 = 0; d3 < 3; ++d3) {
        const int idx = ((z1 + d1) * 4 + (z2 + d2)) * 66 + (z3 + d3);
        mx = fmaxf(mx, a2x[idx]);
        mo = fmaxf(mo, a2o[idx]);
      }
  const bool life = (mx > 0.1f) && (mo > 0.1f);
  if (!life) {
    const int gv = ((b * 64 + z1base + z1) * 64 + (z2base + z2)) * 64 + z3;
    f32x4 z = {0.f, 0.f, 0.f, 0.f};
    #pragma unroll
    for (int j = 0; j < 4; ++j) *(f32x4*)(og + gv * 16 + j * 4) = z;
  }
}

extern "C" void kernel_launch(void* const* d_in, const int* in_sizes, int n_in,
                              void* d_out, int out_size, void* d_ws, size_t ws_size,
                              hipStream_t stream) {
  (void)out_size;
  const void *px = nullptr, *pw0 = nullptr, *pb0 = nullptr, *pw1 = nullptr, *pst = nullptr;
  for (int i = 0; i < n_in; ++i) {
    switch (in_sizes[i]) {
      case 16777216: px  = d_in[i]; break;  // x  [4,64,64,64,16]
      case 8192:     pw0 = d_in[i]; break;  // w0 [128,64]
      case 128:      pb0 = d_in[i]; break;  // b0 [128]
      case 2048:     pw1 = d_in[i]; break;  // w1 [16,128]
      case 1048576:  pst = d_in[i]; break;  // stoch [4,64,64,64,1]
    }
  }
  if (!px || !pw0 || !pb0 || !pw1 || !pst) {
    px = d_in[0]; pw0 = d_in[1]; pb0 = d_in[2]; pw1 = d_in[3]; pst = d_in[4];
  }
  float* outg = (float*)d_out;
  const size_t need = (size_t)VTOT * 4 + (size_t)VTOT;  // fp32 z3-max alpha + byte plife
  const bool use_ws = (d_ws != nullptr) && (ws_size >= need);
  float* aws = use_ws ? (float*)d_ws : nullptr;
  unsigned char* plife = use_ws ? ((unsigned char*)d_ws + (size_t)VTOT * 4) : nullptr;

  nca_main<<<4096, 256, 0, stream>>>((const float*)px, (const float*)pw0, (const float*)pb0,
                                     (const float*)pw1, (const float*)pst, outg, aws, plife);
  if (use_ws)
    nca_life<<<1024, 256, 0, stream>>>(aws, plife, outg);
  else
    nca_life_strided<<<4096, 256, 0, stream>>>((const float*)px, outg, outg);
}

// Round 10
// 242.773 us; speedup vs baseline: 1.7399x; 1.0162x over previous
//
#include <hip/hip_runtime.h>
#include <hip/hip_bf16.h>

typedef unsigned short u16t;
typedef __attribute__((ext_vector_type(8))) short short8;
typedef __attribute__((ext_vector_type(8))) unsigned short ushort8;
typedef __attribute__((ext_vector_type(4))) unsigned short ushort4v;
typedef __attribute__((ext_vector_type(4))) float f32x4;

#define VTOT 1048576

__device__ __forceinline__ float bf2f(u16t u) {
  union { unsigned int i; float f; } v; v.i = ((unsigned int)u) << 16; return v.f;
}
__device__ __forceinline__ u16t f2bf(float f) {
  __hip_bfloat16 h = __float2bfloat16(f);
  union { __hip_bfloat16 b; u16t u; } v; v.b = h; return v.u;
}

// Kernel 1: sobel conv (bf16 LDS, fp32 accum) + fc0(relu) + fc1 via bf16 MFMA + stoch mask.
// R12: R11 single-pass structure + ILP/latency work, spending R11's spare regs
// (VGPR 88 vs measured lb2 arch cap ~124):
//  (1) conv halves z1=0 / z1=1 interleaved manually (was #pragma unroll 1 serial):
//      two independent LDS-load->cvt->fma chains per thread in the dominant phase.
//  (2) w0f/bias loads hoisted before B2; w1f loads before B4: global-load latency
//      drains under barrier waits instead of heading the GEMM phases.
// Occupancy stays 2 waves/SIMD (register law, R4-R10: HW occ == declared
// waves_per_eu; arch cap == budget/2; only lb2 spill-free).
// Spill tripwire: FETCH/WRITE must stay ~67/71MB.
__global__ __launch_bounds__(256, 2) void nca_main(
    const float* __restrict__ xg, const float* __restrict__ w0g,
    const float* __restrict__ b0g, const float* __restrict__ w1g,
    const float* __restrict__ stg, float* __restrict__ outg,
    float* __restrict__ aws, unsigned char* __restrict__ plife)
{
  // region (u16 idx): xs @0 [16 rows(z1,z2)][66 z3][16ch] = 16,896;
  // ys @16,896 [8 kc][256 vox][8] = 16,384; h overlay @0 [256][136] = 34,816.
  __shared__ u16t smem[34816];
  __shared__ float st_l[256];
  __shared__ float alpha_l[256];
  __shared__ unsigned char pl_l[256];

  const int t = threadIdx.x;
  const int bid = blockIdx.x;
  const int b = bid >> 10;
  const int z1base = ((bid >> 5) & 31) * 2;
  const int z2base = (bid & 31) * 2;
  const int YO = 16896;  // ys base (u16)

  {
    int z1 = t >> 7, z2 = (t >> 6) & 1, z3 = t & 63;
    int gv = ((b * 64 + z1base + z1) * 64 + (z2base + z2)) * 64 + z3;
    st_l[t] = stg[gv];
  }

  // stage x halo (fp32 -> bf16): 1056 rows x 16 ch = 4224 float4 chunks
  for (int it = 0; it < 17; ++it) {
    int q = t + it * 256;
    if (q < 4224) {
      int c4 = (q & 3) * 4, s = q >> 2;
      int i3 = s % 66, r = s / 66;
      int i2 = r & 3, i1 = r >> 2;
      int z1g = z1base + i1 - 1, z2g = z2base + i2 - 1, z3g = i3 - 1;
      f32x4 val = {0.f, 0.f, 0.f, 0.f};
      if ((unsigned)z1g < 64u && (unsigned)z2g < 64u && (unsigned)z3g < 64u) {
        int gv = ((b * 64 + z1g) * 64 + z2g) * 64 + z3g;
        val = *(const f32x4*)(xg + gv * 16 + c4);
      }
      ushort4v bv;
      #pragma unroll
      for (int j = 0; j < 4; ++j) bv[j] = f2bf(val[j]);
      *(ushort4v*)(smem + s * 16 + c4) = bv;
    }
  }
  __syncthreads();  // B1: halo staged

  // conv: both z1-halves interleaved — voxA = vq (z1=0), voxB = vq+128 (z1=1);
  // same (z2,z3) => rowB = rowA + 264; two independent dep-chains per thread.
  {
    const int hc = t & 1, vq = t >> 1;           // vq in 0..127
    const int z2 = (vq >> 6) & 1, z3 = vq & 63;
    float axA[8], ayA[8], azA[8], axB[8], ayB[8], azB[8];
    #pragma unroll
    for (int c = 0; c < 8; ++c) {
      axA[c] = 0.f; ayA[c] = 0.f; azA[c] = 0.f;
      axB[c] = 0.f; ayB[c] = 0.f; azB[c] = 0.f;
    }
    ushort8 ctrA{}, ctrB{};
    float amaxA = 0.0f, amaxB = 0.0f;  // alpha>=0; 0-pad same verdict as -inf
    const float W[3] = {1.f, 2.f, 1.f};
    const float D[3] = {-1.f, 0.f, 1.f};
    #pragma unroll
    for (int d1 = 0; d1 < 3; ++d1)
      #pragma unroll
      for (int d2 = 0; d2 < 3; ++d2)
        #pragma unroll
        for (int d3 = 0; d3 < 3; ++d3) {
          const int rowA = ((0 + d1) * 4 + (z2 + d2)) * 66 + (z3 + d3);
          ushort8 uA = *(const ushort8*)(smem + rowA * 16 + hc * 8);
          ushort8 uB = *(const ushort8*)(smem + (rowA + 264) * 16 + hc * 8);
          float fA[8], fB[8];
          #pragma unroll
          for (int c = 0; c < 8; ++c) { fA[c] = bf2f((u16t)uA[c]); fB[c] = bf2f((u16t)uB[c]); }
          const float cx = W[d1] * W[d2] * D[d3] * 0.03125f;  // kx[k,i,j]=w[k]w[i]d[j]/32
          const float cy = W[d1] * D[d2] * W[d3] * 0.03125f;  // ky=kx.T(0,2,1)
          const float cz = D[d1] * W[d2] * W[d3] * 0.03125f;  // kz=kx.T(2,1,0)
          if (cx != 0.f) {
            #pragma unroll
            for (int c = 0; c < 8; ++c) {
              axA[c] = fmaf(fA[c], cx, axA[c]); axB[c] = fmaf(fB[c], cx, axB[c]);
            }
          }
          if (cy != 0.f) {
            #pragma unroll
            for (int c = 0; c < 8; ++c) {
              ayA[c] = fmaf(fA[c], cy, ayA[c]); ayB[c] = fmaf(fB[c], cy, ayB[c]);
            }
          }
          if (cz != 0.f) {
            #pragma unroll
            for (int c = 0; c < 8; ++c) {
              azA[c] = fmaf(fA[c], cz, azA[c]); azB[c] = fmaf(fB[c], cz, azB[c]);
            }
          }
          if (d1 == 1 && d2 == 1 && d3 == 1) { ctrA = uA; ctrB = uB; }
          amaxA = fmaxf(amaxA, fA[3]);
          amaxB = fmaxf(amaxB, fB[3]);
        }
    *(ushort8*)(smem + YO + (0 + hc) * 2048 + vq * 8) = ctrA;
    *(ushort8*)(smem + YO + (0 + hc) * 2048 + (vq + 128) * 8) = ctrB;
    ushort8 bxA, byA, bzA, bxB, byB, bzB;
    #pragma unroll
    for (int c = 0; c < 8; ++c) {
      bxA[c] = (short)f2bf(axA[c]); byA[c] = (short)f2bf(ayA[c]); bzA[c] = (short)f2bf(azA[c]);
      bxB[c] = (short)f2bf(axB[c]); byB[c] = (short)f2bf(ayB[c]); bzB[c] = (short)f2bf(azB[c]);
    }
    *(ushort8*)(smem + YO + (2 + hc) * 2048 + vq * 8) = bxA;
    *(ushort8*)(smem + YO + (4 + hc) * 2048 + vq * 8) = byA;
    *(ushort8*)(smem + YO + (6 + hc) * 2048 + vq * 8) = bzA;
    *(ushort8*)(smem + YO + (2 + hc) * 2048 + (vq + 128) * 8) = bxB;
    *(ushort8*)(smem + YO + (4 + hc) * 2048 + (vq + 128) * 8) = byB;
    *(ushort8*)(smem + YO + (6 + hc) * 2048 + (vq + 128) * 8) = bzB;
    if (hc == 0) {
      pl_l[vq] = (amaxA > 0.1f) ? (unsigned char)1 : (unsigned char)0;
      pl_l[vq + 128] = (amaxB > 0.1f) ? (unsigned char)1 : (unsigned char)0;
    }
  }

  // GEMM prologue hoisted pre-B2: w0 frags + bias issue now, drain under the barrier.
  const int lane = t & 63, w = t >> 6;
  const int col = lane & 15, quad = lane >> 4;
  short8 w0f[2][2];  // w0f[kt][nt][j] = w0[w*32+nt*16+col][kt*32+quad*8+j]
  #pragma unroll
  for (int kt = 0; kt < 2; ++kt)
    #pragma unroll
    for (int nt = 0; nt < 2; ++nt) {
      const float* pw = w0g + (w * 32 + nt * 16 + col) * 64 + kt * 32 + quad * 8;
      f32x4 lo = *(const f32x4*)pw, hi = *(const f32x4*)(pw + 4);
      short8 fr;
      #pragma unroll
      for (int j = 0; j < 4; ++j) { fr[j] = (short)f2bf(lo[j]); fr[4 + j] = (short)f2bf(hi[j]); }
      w0f[kt][nt] = fr;
    }
  f32x4 biasv[2];  // biasv[nt][r] = b0[w*32+nt*16+quad*4+r]
  #pragma unroll
  for (int nt = 0; nt < 2; ++nt)
    biasv[nt] = *(const f32x4*)(b0g + w * 32 + nt * 16 + quad * 4);

  __syncthreads();  // B2: ys complete; xs dead

  // GEMM, N-split fc0: wave w owns h cols [w*32, w*32+32) for all 256 voxels.
  // Swapped MFMA: lane holds h[n=w*32+nt*16+quad*4+r][vox=...+col].
  {
    ushort4v hpk[8][2];  // one vox-half of the wave's h slice: 32 VGPRs

    // fc0 half A: vox 0..127 (mt 0..7)
    #pragma unroll
    for (int mt = 0; mt < 8; ++mt) {
      short8 yf[2];
      #pragma unroll
      for (int kt = 0; kt < 2; ++kt)
        yf[kt] = *(const short8*)(smem + YO + (kt * 4 + quad) * 2048 + (mt * 16 + col) * 8);
      f32x4 acc[2];
      acc[0] = biasv[0]; acc[1] = biasv[1];
      #pragma unroll
      for (int kt = 0; kt < 2; ++kt)
        #pragma unroll
        for (int nt = 0; nt < 2; ++nt)
          acc[nt] = __builtin_amdgcn_mfma_f32_16x16x32_bf16(w0f[kt][nt], yf[kt], acc[nt], 0, 0, 0);
      #pragma unroll
      for (int nt = 0; nt < 2; ++nt) {
        ushort4v hv;
        #pragma unroll
        for (int r = 0; r < 4; ++r) hv[r] = f2bf(fmaxf(acc[nt][r], 0.0f));
        hpk[mt][nt] = hv;
      }
    }
    __syncthreads();  // B3: all waves done reading ys vox 0..127
    // dump half A: h rows 0..127 -> u16 [0, 17,408) (dead xs + dead ys[kc0][vox<64])
    #pragma unroll
    for (int mt = 0; mt < 8; ++mt)
      #pragma unroll
      for (int nt = 0; nt < 2; ++nt)
        *(ushort4v*)(smem + (mt * 16 + col) * 136 + w * 32 + nt * 16 + quad * 4) = hpk[mt][nt];

    // fc0 half B: vox 128..255 (ys regions >= u16 17,920, untouched by dump A)
    #pragma unroll
    for (int mt = 0; mt < 8; ++mt) {
      short8 yf[2];
      #pragma unroll
      for (int kt = 0; kt < 2; ++kt)
        yf[kt] = *(const short8*)(smem + YO + (kt * 4 + quad) * 2048 + (128 + mt * 16 + col) * 8);
      f32x4 acc[2];
      acc[0] = biasv[0]; acc[1] = biasv[1];
      #pragma unroll
      for (int kt = 0; kt < 2; ++kt)
        #pragma unroll
        for (int nt = 0; nt < 2; ++nt)
          acc[nt] = __builtin_amdgcn_mfma_f32_16x16x32_bf16(w0f[kt][nt], yf[kt], acc[nt], 0, 0, 0);
      #pragma unroll
      for (int nt = 0; nt < 2; ++nt) {
        ushort4v hv;
        #pragma unroll
        for (int r = 0; r < 4; ++r) hv[r] = f2bf(fmaxf(acc[nt][r], 0.0f));
        hpk[mt][nt] = hv;
      }
    }

    // w1 frags hoisted pre-B4: loads drain under B4/B5 barrier waits.
    short8 w1f[4];  // B[k][n=col] = w1[col][k]
    #pragma unroll
    for (int kt = 0; kt < 4; ++kt) {
      const float* pw = w1g + col * 128 + kt * 32 + quad * 8;
      f32x4 lo = *(const f32x4*)pw, hi = *(const f32x4*)(pw + 4);
      short8 fr;
      #pragma unroll
      for (int j = 0; j < 4; ++j) { fr[j] = (short)f2bf(lo[j]); fr[4 + j] = (short)f2bf(hi[j]); }
      w1f[kt] = fr;
    }

    __syncthreads();  // B4: all waves done reading ys vox 128..255; dump A visible
    // dump half B: h rows 128..255
    #pragma unroll
    for (int mt = 0; mt < 8; ++mt)
      #pragma unroll
      for (int nt = 0; nt < 2; ++nt)
        *(ushort4v*)(smem + (128 + mt * 16 + col) * 136 + w * 32 + nt * 16 + quad * 4) = hpk[mt][nt];
    __syncthreads();  // B5: full h visible

    // fc1: wave w handles vox [w*64, w*64+64); K=128, N=16
    #pragma unroll
    for (int mt2 = 0; mt2 < 4; ++mt2) {
      const int mbase = w * 64 + mt2 * 16;
      f32x4 dxa = {0.f, 0.f, 0.f, 0.f};
      #pragma unroll
      for (int kt = 0; kt < 4; ++kt) {
        short8 ah = *(const short8*)(smem + (mbase + col) * 136 + kt * 32 + quad * 8);
        dxa = __builtin_amdgcn_mfma_f32_16x16x32_bf16(ah, w1f[kt], dxa, 0, 0, 0);
      }
      // epilogue: out[v][col] = x[v][col] + mask*dx (xg re-read is L2/L3-hot)
      #pragma unroll
      for (int r = 0; r < 4; ++r) {
        const int v = mbase + quad * 4 + r;
        const int z1 = v >> 7, z2 = (v >> 6) & 1, z3 = v & 63;
        const int gv = ((b * 64 + z1base + z1) * 64 + (z2base + z2)) * 64 + z3;
        const int addr = gv * 16 + col;
        float dx = (st_l[v] > 0.5f) ? dxa[r] : 0.0f;
        float x2 = xg[addr] + dx;
        outg[addr] = x2;
        if (col == 3) alpha_l[v] = x2;  // stage fp32 alpha(x2) in LDS
      }
    }
  }
  __syncthreads();  // B6
  // coalesced aux flush; fold the z3 direction of the alive maxpool here:
  // aws[gv] = max(alpha[z3-1], alpha[z3], alpha[z3+1]) (domain edges -> -1e30 sentinel)
  if (aws != nullptr) {
    const int v = t, z3 = t & 63;
    const float a = alpha_l[v];
    const float up = (z3 > 0) ? alpha_l[v - 1] : -1e30f;
    const float dn = (z3 < 63) ? alpha_l[v + 1] : -1e30f;
    const int gv = ((b * 64 + z1base + (v >> 7)) * 64 + (z2base + ((v >> 6) & 1))) * 64 + z3;
    aws[gv] = fmaxf(a, fmaxf(up, dn));
    plife[gv] = pl_l[v];
  }
}

// Kernel 2 (4 tiles/block): life = plife & (max over 3x3 (z1,z2) rows of
// z3-premaxed aws > 0.1); zero dead voxels.  Each block: 4x4 (z1,z2) x 64 z3
// = 1024 voxels; halo staging 36 rows; grid 1024.
__global__ void nca_life(const float* __restrict__ aws,
                         const unsigned char* __restrict__ plife,
                         float* __restrict__ og)
{
  __shared__ float m3s[2304];  // [36 rows][64] z3-premaxed alpha(x2)
  const int t = threadIdx.x, bid = blockIdx.x;
  const int b = bid >> 8;
  const int z1b = ((bid >> 4) & 15) * 4;
  const int z2b = (bid & 15) * 4;
  #pragma unroll
  for (int it = 0; it < 9; ++it) {
    const int q = t + it * 256;           // 0..2303
    const int row = q >> 6, z3 = q & 63;  // row = r1*6 + r2, 6x6 halo grid
    const int r1 = z1b + (row / 6) - 1, r2 = z2b + (row % 6) - 1;
    float a = -1e30f;
    if ((unsigned)r1 < 64u && (unsigned)r2 < 64u)
      a = aws[((b * 64 + r1) * 64 + r2) * 64 + z3];
    m3s[q] = a;
  }
  // prefetch plife (coalesced) while staging is in flight
  unsigned char pl[4]; int gvs[4];
  #pragma unroll
  for (int k = 0; k < 4; ++k) {
    const int v = t + k * 256;
    const int z1l = v >> 8, z2l = (v >> 6) & 3, z3 = v & 63;
    gvs[k] = ((b * 64 + z1b + z1l) * 64 + (z2b + z2l)) * 64 + z3;
    pl[k] = plife[gvs[k]];
  }
  __syncthreads();
  #pragma unroll
  for (int k = 0; k < 4; ++k) {
    const int v = t + k * 256;
    const int z1l = v >> 8, z2l = (v >> 6) & 3, z3 = v & 63;
    float mo = -1e30f;
    #pragma unroll
    for (int d1 = 0; d1 < 3; ++d1)
      #pragma unroll
      for (int d2 = 0; d2 < 3; ++d2)
        mo = fmaxf(mo, m3s[((z1l + d1) * 6 + (z2l + d2)) * 64 + z3]);
    const bool life = (pl[k] != 0) && (mo > 0.1f);
    if (!life) {
      f32x4 z = {0.f, 0.f, 0.f, 0.f};
      #pragma unroll
      for (int j = 0; j < 4; ++j) *(f32x4*)(og + gvs[k] * 16 + j * 4) = z;
    }
  }
}

// Fallback (no workspace): recompute both alive masks from strided global reads.
__global__ void nca_life_strided(const float* __restrict__ xg, const float* __restrict__ outg,
                                 float* __restrict__ og)
{
  __shared__ float a2x[1056];
  __shared__ float a2o[1056];
  const int t = threadIdx.x, bid = blockIdx.x;
  const int b = bid >> 10;
  const int z1base = ((bid >> 5) & 31) * 2;
  const int z2base = (bid & 31) * 2;
  for (int it = 0; it < 5; ++it) {
    int q = t + it * 256;
    if (q < 1056) {
      int i3 = q % 66, r = q / 66;
      int i2 = r & 3, i1 = r >> 2;
      int z1g = z1base + i1 - 1, z2g = z2base + i2 - 1, z3g = i3 - 1;
      float vx = 0.f, vo = 0.f;
      if ((unsigned)z1g < 64u && (unsigned)z2g < 64u && (unsigned)z3g < 64u) {
        int gv = ((b * 64 + z1g) * 64 + z2g) * 64 + z3g;
        vx = xg[gv * 16 + 3];
        vo = outg[gv * 16 + 3];
      }
      a2x[q] = vx; a2o[q] = vo;
    }
  }
  __syncthreads();
  const int z1 = t >> 7, z2 = (t >> 6) & 1, z3 = t & 63;
  float mx = -1e30f, mo = -1e30f;
  #pragma unroll
  for (int d1 = 0; d1 < 3; ++d1)
    #pragma unroll
    for (int d2 = 0; d2 < 3; ++d2)
      #pragma unroll
      for (int d3 = 0; d3 < 3; ++d3) {
        const int idx = ((z1 + d1) * 4 + (z2 + d2)) * 66 + (z3 + d3);
        mx = fmaxf(mx, a2x[idx]);
        mo = fmaxf(mo, a2o[idx]);
      }
  const bool life = (mx > 0.1f) && (mo > 0.1f);
  if (!life) {
    const int gv = ((b * 64 + z1base + z1) * 64 + (z2base + z2)) * 64 + z3;
    f32x4 z = {0.f, 0.f, 0.f, 0.f};
    #pragma unroll
    for (int j = 0; j < 4; ++j) *(f32x4*)(og + gv * 16 + j * 4) = z;
  }
}

extern "C" void kernel_launch(void* const* d_in, const int* in_sizes, int n_in,
                              void* d_out, int out_size, void* d_ws, size_t ws_size,
                              hipStream_t stream) {
  (void)out_size;
  const void *px = nullptr, *pw0 = nullptr, *pb0 = nullptr, *pw1 = nullptr, *pst = nullptr;
  for (int i = 0; i < n_in; ++i) {
    switch (in_sizes[i]) {
      case 16777216: px  = d_in[i]; break;  // x  [4,64,64,64,16]
      case 8192:     pw0 = d_in[i]; break;  // w0 [128,64]
      case 128:      pb0 = d_in[i]; break;  // b0 [128]
      case 2048:     pw1 = d_in[i]; break;  // w1 [16,128]
      case 1048576:  pst = d_in[i]; break;  // stoch [4,64,64,64,1]
    }
  }
  if (!px || !pw0 || !pb0 || !pw1 || !pst) {
    px = d_in[0]; pw0 = d_in[1]; pb0 = d_in[2]; pw1 = d_in[3]; pst = d_in[4];
  }
  float* outg = (float*)d_out;
  const size_t need = (size_t)VTOT * 4 + (size_t)VTOT;  // fp32 z3-max alpha + byte plife
  const bool use_ws = (d_ws != nullptr) && (ws_size >= need);
  float* aws = use_ws ? (float*)d_ws : nullptr;
  unsigned char* plife = use_ws ? ((unsigned char*)d_ws + (size_t)VTOT * 4) : nullptr;

  nca_main<<<4096, 256, 0, stream>>>((const float*)px, (const float*)pw0, (const float*)pb0,
                                     (const float*)pw1, (const float*)pst, outg, aws, plife);
  if (use_ws)
    nca_life<<<1024, 256, 0, stream>>>(aws, plife, outg);
  else
    nca_life_strided<<<4096, 256, 0, stream>>>((const float*)px, outg, outg);
}

// Round 11
// 202.068 us; speedup vs baseline: 2.0904x; 1.2014x over previous
//
#include <hip/hip_runtime.h>
#include <hip/hip_bf16.h>

typedef unsigned short u16t;
typedef __attribute__((ext_vector_type(8))) short short8;
typedef __attribute__((ext_vector_type(8))) unsigned short ushort8;
typedef __attribute__((ext_vector_type(4))) unsigned short ushort4v;
typedef __attribute__((ext_vector_type(4))) float f32x4;

#define VTOT 1048576

__device__ __forceinline__ float bf2f(u16t u) {
  union { unsigned int i; float f; } v; v.i = ((unsigned int)u) << 16; return v.f;
}
__device__ __forceinline__ u16t f2bf(float f) {
  __hip_bfloat16 h = __float2bfloat16(f);
  union { __hip_bfloat16 b; u16t u; } v; v.b = h; return v.u;
}

// Kernel 1: sobel conv (bf16 LDS, fp32 accum) + fc0(relu) + fc1 via bf16 MFMA + stoch mask.
// R13: critical-path surgery on the R12 skeleton (occupancy locked at 2 waves/SIMD:
// LDS 72KB -> 2 blocks/CU, and the measured lb-law blocks register routes).
//  (1) h stride 136 -> 132: dump-A (h rows 0..127) = u16 [0,16896) = EXACTLY dead xs
//      -> barrier B3 deleted (6 -> 5 barriers).  Stride 132 also makes fc1 reads
//      bank-conflict-free (bank = 2*col mod 32).
//  (2) div-free staging: direct (row,z3,half) iteration, 8 dense iters + 64-thread
//      zero-write for the always-OOB z3 edge planes (z3 is full-depth; +-1 is global pad).
//  (3) all 16 epilogue xg loads hoisted before B4: L2 latency drains under
//      dump-B/B4/B5/fc1.  Regs free: LDS caps occupancy; <=256 keeps 2 waves.
// Spill tripwire: FETCH/WRITE must stay ~67/71MB.
__global__ __launch_bounds__(256, 2) void nca_main(
    const float* __restrict__ xg, const float* __restrict__ w0g,
    const float* __restrict__ b0g, const float* __restrict__ w1g,
    const float* __restrict__ stg, float* __restrict__ outg,
    float* __restrict__ aws, unsigned char* __restrict__ plife)
{
  // region (u16 idx): xs @0 [16 rows(z1,z2)][66 z3][16ch] = 16,896;
  // ys @16,896 [8 kc][256 vox][8] = 16,384 (ends 33,280);
  // h overlay @0 [256 vox][132] = 33,792.
  __shared__ u16t smem[33792];
  __shared__ float st_l[256];
  __shared__ float alpha_l[256];
  __shared__ unsigned char pl_l[256];

  const int t = threadIdx.x;
  const int bid = blockIdx.x;
  const int b = bid >> 10;
  const int z1base = ((bid >> 5) & 31) * 2;
  const int z2base = (bid & 31) * 2;
  const int YO = 16896;  // ys base (u16)

  {
    int z1 = t >> 7, z2 = (t >> 6) & 1, z3 = t & 63;
    int gv = ((b * 64 + z1base + z1) * 64 + (z2base + z2)) * 64 + z3;
    st_l[t] = stg[gv];
  }

  // stage x halo (fp32 -> bf16), div-free: interior i3=1..64 via (row, z3g, half),
  // 8 iters x (2 f32x4 loads -> 1 ushort8 LDS write, dense across lanes).
  #pragma unroll
  for (int it = 0; it < 8; ++it) {
    const int row = it * 2 + (t >> 7);          // 0..15 = (i1*4+i2)
    const int z3g = (t >> 1) & 63;
    const int half = t & 1;
    const int z1g = z1base + (row >> 2) - 1, z2g = z2base + (row & 3) - 1;
    f32x4 v0 = {0.f, 0.f, 0.f, 0.f}, v1 = {0.f, 0.f, 0.f, 0.f};
    if ((unsigned)z1g < 64u && (unsigned)z2g < 64u) {
      const float* p = xg + ((((b * 64 + z1g) * 64 + z2g) * 64 + z3g) * 16) + half * 8;
      v0 = *(const f32x4*)p;
      v1 = *(const f32x4*)(p + 4);
    }
    ushort8 pk;
    #pragma unroll
    for (int j = 0; j < 4; ++j) { pk[j] = f2bf(v0[j]); pk[4 + j] = f2bf(v1[j]); }
    *(ushort8*)(smem + (row * 66 + z3g + 1) * 16 + half * 8) = pk;
  }
  // z3 edge planes i3=0,65 (z3g=-1,64 are outside the global domain -> zero pad)
  if (t < 64) {
    const int row = t >> 2, edge = (t >> 1) & 1, half = t & 1;
    ushort8 z{};
    *(ushort8*)(smem + (row * 66 + edge * 65) * 16 + half * 8) = z;
  }
  __syncthreads();  // B1: halo staged

  // conv: both z1-halves interleaved — voxA = vq (z1=0), voxB = vq+128 (z1=1);
  // same (z2,z3) => rowB = rowA + 264; two independent dep-chains per thread.
  {
    const int hc = t & 1, vq = t >> 1;           // vq in 0..127
    const int z2 = (vq >> 6) & 1, z3 = vq & 63;
    float axA[8], ayA[8], azA[8], axB[8], ayB[8], azB[8];
    #pragma unroll
    for (int c = 0; c < 8; ++c) {
      axA[c] = 0.f; ayA[c] = 0.f; azA[c] = 0.f;
      axB[c] = 0.f; ayB[c] = 0.f; azB[c] = 0.f;
    }
    ushort8 ctrA{}, ctrB{};
    float amaxA = 0.0f, amaxB = 0.0f;  // alpha>=0; 0-pad same verdict as -inf
    const float W[3] = {1.f, 2.f, 1.f};
    const float D[3] = {-1.f, 0.f, 1.f};
    #pragma unroll
    for (int d1 = 0; d1 < 3; ++d1)
      #pragma unroll
      for (int d2 = 0; d2 < 3; ++d2)
        #pragma unroll
        for (int d3 = 0; d3 < 3; ++d3) {
          const int rowA = ((0 + d1) * 4 + (z2 + d2)) * 66 + (z3 + d3);
          ushort8 uA = *(const ushort8*)(smem + rowA * 16 + hc * 8);
          ushort8 uB = *(const ushort8*)(smem + (rowA + 264) * 16 + hc * 8);
          float fA[8], fB[8];
          #pragma unroll
          for (int c = 0; c < 8; ++c) { fA[c] = bf2f((u16t)uA[c]); fB[c] = bf2f((u16t)uB[c]); }
          const float cx = W[d1] * W[d2] * D[d3] * 0.03125f;  // kx[k,i,j]=w[k]w[i]d[j]/32
          const float cy = W[d1] * D[d2] * W[d3] * 0.03125f;  // ky=kx.T(0,2,1)
          const float cz = D[d1] * W[d2] * W[d3] * 0.03125f;  // kz=kx.T(2,1,0)
          if (cx != 0.f) {
            #pragma unroll
            for (int c = 0; c < 8; ++c) {
              axA[c] = fmaf(fA[c], cx, axA[c]); axB[c] = fmaf(fB[c], cx, axB[c]);
            }
          }
          if (cy != 0.f) {
            #pragma unroll
            for (int c = 0; c < 8; ++c) {
              ayA[c] = fmaf(fA[c], cy, ayA[c]); ayB[c] = fmaf(fB[c], cy, ayB[c]);
            }
          }
          if (cz != 0.f) {
            #pragma unroll
            for (int c = 0; c < 8; ++c) {
              azA[c] = fmaf(fA[c], cz, azA[c]); azB[c] = fmaf(fB[c], cz, azB[c]);
            }
          }
          if (d1 == 1 && d2 == 1 && d3 == 1) { ctrA = uA; ctrB = uB; }
          amaxA = fmaxf(amaxA, fA[3]);
          amaxB = fmaxf(amaxB, fB[3]);
        }
    *(ushort8*)(smem + YO + (0 + hc) * 2048 + vq * 8) = ctrA;
    *(ushort8*)(smem + YO + (0 + hc) * 2048 + (vq + 128) * 8) = ctrB;
    ushort8 bxA, byA, bzA, bxB, byB, bzB;
    #pragma unroll
    for (int c = 0; c < 8; ++c) {
      bxA[c] = f2bf(axA[c]); byA[c] = f2bf(ayA[c]); bzA[c] = f2bf(azA[c]);
      bxB[c] = f2bf(axB[c]); byB[c] = f2bf(ayB[c]); bzB[c] = f2bf(azB[c]);
    }
    *(ushort8*)(smem + YO + (2 + hc) * 2048 + vq * 8) = bxA;
    *(ushort8*)(smem + YO + (4 + hc) * 2048 + vq * 8) = byA;
    *(ushort8*)(smem + YO + (6 + hc) * 2048 + vq * 8) = bzA;
    *(ushort8*)(smem + YO + (2 + hc) * 2048 + (vq + 128) * 8) = bxB;
    *(ushort8*)(smem + YO + (4 + hc) * 2048 + (vq + 128) * 8) = byB;
    *(ushort8*)(smem + YO + (6 + hc) * 2048 + (vq + 128) * 8) = bzB;
    if (hc == 0) {
      pl_l[vq] = (amaxA > 0.1f) ? (unsigned char)1 : (unsigned char)0;
      pl_l[vq + 128] = (amaxB > 0.1f) ? (unsigned char)1 : (unsigned char)0;
    }
  }

  // GEMM prologue hoisted pre-B2: w0 frags + bias issue now, drain under the barrier.
  const int lane = t & 63, w = t >> 6;
  const int col = lane & 15, quad = lane >> 4;
  short8 w0f[2][2];  // w0f[kt][nt][j] = w0[w*32+nt*16+col][kt*32+quad*8+j]
  #pragma unroll
  for (int kt = 0; kt < 2; ++kt)
    #pragma unroll
    for (int nt = 0; nt < 2; ++nt) {
      const float* pw = w0g + (w * 32 + nt * 16 + col) * 64 + kt * 32 + quad * 8;
      f32x4 lo = *(const f32x4*)pw, hi = *(const f32x4*)(pw + 4);
      short8 fr;
      #pragma unroll
      for (int j = 0; j < 4; ++j) { fr[j] = (short)f2bf(lo[j]); fr[4 + j] = (short)f2bf(hi[j]); }
      w0f[kt][nt] = fr;
    }
  f32x4 biasv[2];  // biasv[nt][r] = b0[w*32+nt*16+quad*4+r]
  #pragma unroll
  for (int nt = 0; nt < 2; ++nt)
    biasv[nt] = *(const f32x4*)(b0g + w * 32 + nt * 16 + quad * 4);

  __syncthreads();  // B2: ys complete; xs dead

  // GEMM, N-split fc0: wave w owns h cols [w*32, w*32+32) for all 256 voxels.
  // Swapped MFMA: lane holds h[n=w*32+nt*16+quad*4+r][vox=...+col].
  {
    ushort4v hpk[8][2];  // one vox-half of the wave's h slice: 32 VGPRs

    // fc0 half A: vox 0..127 (mt 0..7)
    #pragma unroll
    for (int mt = 0; mt < 8; ++mt) {
      short8 yf[2];
      #pragma unroll
      for (int kt = 0; kt < 2; ++kt)
        yf[kt] = *(const short8*)(smem + YO + (kt * 4 + quad) * 2048 + (mt * 16 + col) * 8);
      f32x4 acc[2];
      acc[0] = biasv[0]; acc[1] = biasv[1];
      #pragma unroll
      for (int kt = 0; kt < 2; ++kt)
        #pragma unroll
        for (int nt = 0; nt < 2; ++nt)
          acc[nt] = __builtin_amdgcn_mfma_f32_16x16x32_bf16(w0f[kt][nt], yf[kt], acc[nt], 0, 0, 0);
      #pragma unroll
      for (int nt = 0; nt < 2; ++nt) {
        ushort4v hv;
        #pragma unroll
        for (int r = 0; r < 4; ++r) hv[r] = f2bf(fmaxf(acc[nt][r], 0.0f));
        hpk[mt][nt] = hv;
      }
    }
    // dump half A immediately (NO barrier): h rows 0..127 @ stride 132 = u16 [0,16896)
    // = exactly the dead xs region; ys untouched, other waves' h-columns disjoint.
    #pragma unroll
    for (int mt = 0; mt < 8; ++mt)
      #pragma unroll
      for (int nt = 0; nt < 2; ++nt)
        *(ushort4v*)(smem + (mt * 16 + col) * 132 + w * 32 + nt * 16 + quad * 4) = hpk[mt][nt];

    // fc0 half B: vox 128..255 (ys only; dump-A region disjoint)
    #pragma unroll
    for (int mt = 0; mt < 8; ++mt) {
      short8 yf[2];
      #pragma unroll
      for (int kt = 0; kt < 2; ++kt)
        yf[kt] = *(const short8*)(smem + YO + (kt * 4 + quad) * 2048 + (128 + mt * 16 + col) * 8);
      f32x4 acc[2];
      acc[0] = biasv[0]; acc[1] = biasv[1];
      #pragma unroll
      for (int kt = 0; kt < 2; ++kt)
        #pragma unroll
        for (int nt = 0; nt < 2; ++nt)
          acc[nt] = __builtin_amdgcn_mfma_f32_16x16x32_bf16(w0f[kt][nt], yf[kt], acc[nt], 0, 0, 0);
      #pragma unroll
      for (int nt = 0; nt < 2; ++nt) {
        ushort4v hv;
        #pragma unroll
        for (int r = 0; r < 4; ++r) hv[r] = f2bf(fmaxf(acc[nt][r], 0.0f));
        hpk[mt][nt] = hv;
      }
    }

    // epilogue x-values hoisted: 16 L2-hot loads issued here, drain under dump-B/B4/B5/fc1.
    float xv[16];
    #pragma unroll
    for (int mt2 = 0; mt2 < 4; ++mt2)
      #pragma unroll
      for (int r = 0; r < 4; ++r) {
        const int v = w * 64 + mt2 * 16 + quad * 4 + r;
        const int z1 = v >> 7, z2 = (v >> 6) & 1, z3 = v & 63;
        const int gv = ((b * 64 + z1base + z1) * 64 + (z2base + z2)) * 64 + z3;
        xv[mt2 * 4 + r] = xg[gv * 16 + col];
      }

    // w1 frags: loads drain under B4/B5 barrier waits.
    short8 w1f[4];  // B[k][n=col] = w1[col][k]
    #pragma unroll
    for (int kt = 0; kt < 4; ++kt) {
      const float* pw = w1g + col * 128 + kt * 32 + quad * 8;
      f32x4 lo = *(const f32x4*)pw, hi = *(const f32x4*)(pw + 4);
      short8 fr;
      #pragma unroll
      for (int j = 0; j < 4; ++j) { fr[j] = (short)f2bf(lo[j]); fr[4 + j] = (short)f2bf(hi[j]); }
      w1f[kt] = fr;
    }

    __syncthreads();  // B4: all waves done reading ys; dump A visible
    // dump half B: h rows 128..255 @ stride 132 -> u16 [16896, 33792) (dead ys)
    #pragma unroll
    for (int mt = 0; mt < 8; ++mt)
      #pragma unroll
      for (int nt = 0; nt < 2; ++nt)
        *(ushort4v*)(smem + (128 + mt * 16 + col) * 132 + w * 32 + nt * 16 + quad * 4) = hpk[mt][nt];
    __syncthreads();  // B5: full h visible

    // fc1: wave w handles vox [w*64, w*64+64); K=128, N=16; stride-132 reads are
    // bank-conflict-free (bank = 2*col mod 32, distinct for col 0..15).
    #pragma unroll
    for (int mt2 = 0; mt2 < 4; ++mt2) {
      const int mbase = w * 64 + mt2 * 16;
      f32x4 dxa = {0.f, 0.f, 0.f, 0.f};
      #pragma unroll
      for (int kt = 0; kt < 4; ++kt) {
        short8 ah = *(const short8*)(smem + (mbase + col) * 132 + kt * 32 + quad * 8);
        dxa = __builtin_amdgcn_mfma_f32_16x16x32_bf16(ah, w1f[kt], dxa, 0, 0, 0);
      }
      // epilogue: out[v][col] = xv + mask*dx
      #pragma unroll
      for (int r = 0; r < 4; ++r) {
        const int v = mbase + quad * 4 + r;
        const int z1 = v >> 7, z2 = (v >> 6) & 1, z3 = v & 63;
        const int gv = ((b * 64 + z1base + z1) * 64 + (z2base + z2)) * 64 + z3;
        const int addr = gv * 16 + col;
        float dx = (st_l[v] > 0.5f) ? dxa[r] : 0.0f;
        float x2 = xv[mt2 * 4 + r] + dx;
        outg[addr] = x2;
        if (col == 3) alpha_l[v] = x2;  // stage fp32 alpha(x2) in LDS
      }
    }
  }
  __syncthreads();  // B6
  // coalesced aux flush; fold the z3 direction of the alive maxpool here:
  // aws[gv] = max(alpha[z3-1], alpha[z3], alpha[z3+1]) (domain edges -> -1e30 sentinel)
  if (aws != nullptr) {
    const int v = t, z3 = t & 63;
    const float a = alpha_l[v];
    const float up = (z3 > 0) ? alpha_l[v - 1] : -1e30f;
    const float dn = (z3 < 63) ? alpha_l[v + 1] : -1e30f;
    const int gv = ((b * 64 + z1base + (v >> 7)) * 64 + (z2base + ((v >> 6) & 1))) * 64 + z3;
    aws[gv] = fmaxf(a, fmaxf(up, dn));
    plife[gv] = pl_l[v];
  }
}

// Kernel 2 (4 tiles/block): life = plife & (max over 3x3 (z1,z2) rows of
// z3-premaxed aws > 0.1); zero dead voxels.  Each block: 4x4 (z1,z2) x 64 z3
// = 1024 voxels; halo staging 36 rows; grid 1024.
__global__ void nca_life(const float* __restrict__ aws,
                         const unsigned char* __restrict__ plife,
                         float* __restrict__ og)
{
  __shared__ float m3s[2304];  // [36 rows][64] z3-premaxed alpha(x2)
  const int t = threadIdx.x, bid = blockIdx.x;
  const int b = bid >> 8;
  const int z1b = ((bid >> 4) & 15) * 4;
  const int z2b = (bid & 15) * 4;
  #pragma unroll
  for (int it = 0; it < 9; ++it) {
    const int q = t + it * 256;           // 0..2303
    const int row = q >> 6, z3 = q & 63;  // row = r1*6 + r2, 6x6 halo grid
    const int r1 = z1b + (row / 6) - 1, r2 = z2b + (row % 6) - 1;
    float a = -1e30f;
    if ((unsigned)r1 < 64u && (unsigned)r2 < 64u)
      a = aws[((b * 64 + r1) * 64 + r2) * 64 + z3];
    m3s[q] = a;
  }
  // prefetch plife (coalesced) while staging is in flight
  unsigned char pl[4]; int gvs[4];
  #pragma unroll
  for (int k = 0; k < 4; ++k) {
    const int v = t + k * 256;
    const int z1l = v >> 8, z2l = (v >> 6) & 3, z3 = v & 63;
    gvs[k] = ((b * 64 + z1b + z1l) * 64 + (z2b + z2l)) * 64 + z3;
    pl[k] = plife[gvs[k]];
  }
  __syncthreads();
  #pragma unroll
  for (int k = 0; k < 4; ++k) {
    const int v = t + k * 256;
    const int z1l = v >> 8, z2l = (v >> 6) & 3, z3 = v & 63;
    float mo = -1e30f;
    #pragma unroll
    for (int d1 = 0; d1 < 3; ++d1)
      #pragma unroll
      for (int d2 = 0; d2 < 3; ++d2)
        mo = fmaxf(mo, m3s[((z1l + d1) * 6 + (z2l + d2)) * 64 + z3]);
    const bool life = (pl[k] != 0) && (mo > 0.1f);
    if (!life) {
      f32x4 z = {0.f, 0.f, 0.f, 0.f};
      #pragma unroll
      for (int j = 0; j < 4; ++j) *(f32x4*)(og + gvs[k] * 16 + j * 4) = z;
    }
  }
}

// Fallback (no workspace): recompute both alive masks from strided global reads.
__global__ void nca_life_strided(const float* __restrict__ xg, const float* __restrict__ outg,
                                 float* __restrict__ og)
{
  __shared__ float a2x[1056];
  __shared__ float a2o[1056];
  const int t = threadIdx.x, bid = blockIdx.x;
  const int b = bid >> 10;
  const int z1base = ((bid >> 5) & 31) * 2;
  const int z2base = (bid & 31) * 2;
  for (int it = 0; it < 5; ++it) {
    int q = t + it * 256;
    if (q < 1056) {
      int i3 = q % 66, r = q / 66;
      int i2 = r & 3, i1 = r >> 2;
      int z1g = z1base + i1 - 1, z2g = z2base + i2 - 1, z3g = i3 - 1;
      float vx = 0.f, vo = 0.f;
      if ((unsigned)z1g < 64u && (unsigned)z2g < 64u && (unsigned)z3g < 64u) {
        int gv = ((b * 64 + z1g) * 64 + z2g) * 64 + z3g;
        vx = xg[gv * 16 + 3];
        vo = outg[gv * 16 + 3];
      }
      a2x[q] = vx; a2o[q] = vo;
    }
  }
  __syncthreads();
  const int z1 = t >> 7, z2 = (t >> 6) & 1, z3 = t & 63;
  float mx = -1e30f, mo = -1e30f;
  #pragma unroll
  for (int d1 = 0; d1 < 3; ++d1)
    #pragma unroll
    for (int d2 = 0; d2 < 3; ++d2)
      #pragma unroll
      for (int d3 = 0; d3 < 3; ++d3) {
        const int idx = ((z1 + d1) * 4 + (z2 + d2)) * 66 + (z3 + d3);
        mx = fmaxf(mx, a2x[idx]);
        mo = fmaxf(mo, a2o[idx]);
      }
  const bool life = (mx > 0.1f) && (mo > 0.1f);
  if (!life) {
    const int gv = ((b * 64 + z1base + z1) * 64 + (z2base + z2)) * 64 + z3;
    f32x4 z = {0.f, 0.f, 0.f, 0.f};
    #pragma unroll
    for (int j = 0; j < 4; ++j) *(f32x4*)(og + gv * 16 + j * 4) = z;
  }
}

extern "C" void kernel_launch(void* const* d_in, const int* in_sizes, int n_in,
                              void* d_out, int out_size, void* d_ws, size_t ws_size,
                              hipStream_t stream) {
  (void)out_size;
  const void *px = nullptr, *pw0 = nullptr, *pb0 = nullptr, *pw1 = nullptr, *pst = nullptr;
  for (int i = 0; i < n_in; ++i) {
    switch (in_sizes[i]) {
      case 16777216: px  = d_in[i]; break;  // x  [4,64,64,64,16]
      case 8192:     pw0 = d_in[i]; break;  // w0 [128,64]
      case 128:      pb0 = d_in[i]; break;  // b0 [128]
      case 2048:     pw1 = d_in[i]; break;  // w1 [16,128]
      case 1048576:  pst = d_in[i]; break;  // stoch [4,64,64,64,1]
    }
  }
  if (!px || !pw0 || !pb0 || !pw1 || !pst) {
    px = d_in[0]; pw0 = d_in[1]; pb0 = d_in[2]; pw1 = d_in[3]; pst = d_in[4];
  }
  float* outg = (float*)d_out;
  const size_t need = (size_t)VTOT * 4 + (size_t)VTOT;  // fp32 z3-max alpha + byte plife
  const bool use_ws = (d_ws != nullptr) && (ws_size >= need);
  float* aws = use_ws ? (float*)d_ws : nullptr;
  unsigned char* plife = use_ws ? ((unsigned char*)d_ws + (size_t)VTOT * 4) : nullptr;

  nca_main<<<4096, 256, 0, stream>>>((const float*)px, (const float*)pw0, (const float*)pb0,
                                     (const float*)pw1, (const float*)pst, outg, aws, plife);
  if (use_ws)
    nca_life<<<1024, 256, 0, stream>>>(aws, plife, outg);
  else
    nca_life_strided<<<4096, 256, 0, stream>>>((const float*)px, outg, outg);
}